// Round 6
// baseline (228.788 us; speedup 1.0000x reference)
//
#include <hip/hip_runtime.h>

#define NU 120000
#define NI 80000
#define NN 200000
#define DD 64
#define NE 1280000
#define BB 4096
#define NS 8192   // 2*B sampled nodes
#define NB 782    // ceil(NN/256) buckets, bucket = dst>>8
#define CHUNK 8192

// ---------------- bucket histogram (782 LDS counters, merge via global atomics) ----------------
__global__ void k_bhist(const int* __restrict__ dst, int* __restrict__ bcount) {
  __shared__ int h[NB];
  for (int i = threadIdx.x; i < NB; i += 256) h[i] = 0;
  __syncthreads();
  int e0 = blockIdx.x * CHUNK;
#pragma unroll
  for (int k = 0; k < CHUNK / 256; ++k) {
    int e = e0 + k * 256 + threadIdx.x;
    if (e < NE) atomicAdd(&h[dst[e] >> 8], 1);
  }
  __syncthreads();
  for (int i = threadIdx.x; i < NB; i += 256)
    if (h[i]) atomicAdd(&bcount[i], h[i]);
}

// single-block scan of 782 bucket counts -> bbase (exclusive), init bcur
__global__ void k_bscan(const int* __restrict__ bcount, int* __restrict__ bbase,
                        int* __restrict__ bcur, int* __restrict__ row_ptr) {
  __shared__ int s[1024];
  int t = threadIdx.x;
  int x = (t < NB) ? bcount[t] : 0;
  s[t] = x;
  __syncthreads();
  for (int off = 1; off < 1024; off <<= 1) {
    int v = (t >= off) ? s[t - off] : 0;
    __syncthreads();
    s[t] += v;
    __syncthreads();
  }
  if (t < NB) {
    int e = s[t] - x;
    bbase[t] = e;
    bcur[t] = e;
  }
  if (t == 0) {
    bbase[NB] = NE;
    row_ptr[NN] = NE;
  }
}

// ---------------- two-phase bucketed scatter ----------------
__global__ void k_coarse(const int* __restrict__ src, const int* __restrict__ dst,
                         const float* __restrict__ val, int* __restrict__ bcur,
                         int2* __restrict__ c_sv, int* __restrict__ c_dst) {
  __shared__ int hist[NB];
  __shared__ int base[NB];
  int tid = threadIdx.x;
  int e0 = blockIdx.x * CHUNK;
  for (int i = tid; i < NB; i += 256) hist[i] = 0;
  __syncthreads();
#pragma unroll
  for (int k = 0; k < CHUNK / 256; ++k) {
    int e = e0 + k * 256 + tid;
    if (e < NE) atomicAdd(&hist[dst[e] >> 8], 1);
  }
  __syncthreads();
  for (int i = tid; i < NB; i += 256) {
    int h = hist[i];
    base[i] = h ? atomicAdd(&bcur[i], h) : 0;
    hist[i] = 0;
  }
  __syncthreads();
#pragma unroll
  for (int k = 0; k < CHUNK / 256; ++k) {
    int e = e0 + k * 256 + tid;
    if (e < NE) {
      int d = dst[e];
      int b = d >> 8;
      int pos = base[b] + atomicAdd(&hist[b], 1);
      c_sv[pos] = make_int2(src[e], __float_as_int(val[e]));
      c_dst[pos] = d;
    }
  }
}

// Phase 2: one block per bucket; per-node counts+scan in LDS; writes row_ptr AND pairs.
__global__ void k_fine2(const int* __restrict__ bbase, const int2* __restrict__ c_sv,
                        const int* __restrict__ c_dst, int2* __restrict__ pairs,
                        int* __restrict__ row_ptr) {
  __shared__ int cnt[256];
  __shared__ int pre[256];
  __shared__ int cur[256];
  int b = blockIdx.x;
  int node0 = b << 8;
  int t = threadIdx.x;
  cnt[t] = 0;
  __syncthreads();
  int start = bbase[b], end = bbase[b + 1];
  for (int e = start + t; e < end; e += 256) atomicAdd(&cnt[c_dst[e] - node0], 1);
  __syncthreads();
  int x = cnt[t];
  pre[t] = x;
  __syncthreads();
  for (int off = 1; off < 256; off <<= 1) {
    int v = (t >= off) ? pre[t - off] : 0;
    __syncthreads();
    pre[t] += v;
    __syncthreads();
  }
  int node = node0 + t;
  if (node < NN) row_ptr[node] = start + pre[t] - x;  // exclusive prefix
  cur[t] = 0;
  __syncthreads();
  for (int e = start + t; e < end; e += 256) {
    int d = c_dst[e];
    int loc = d - node0;
    int off = atomicAdd(&cur[loc], 1);
    pairs[start + pre[loc] - cnt[loc] + off] = c_sv[e];
  }
}

// ---------------- sample node list ----------------
__global__ void k_build_s(const int* __restrict__ u, const int* __restrict__ ii,
                          int* __restrict__ snodes) {
  int t = blockIdx.x * 256 + threadIdx.x;
  if (t < NS) snodes[t] = (t < BB) ? u[t] : NU + ii[t - BB];
}

// ---------------- frontier marking ----------------
__global__ void k_mark_s(const int* __restrict__ snodes, const int* __restrict__ row_ptr,
                         const int2* __restrict__ pairs, int* __restrict__ need1,
                         int* __restrict__ need2) {
  int t = blockIdx.x * blockDim.x + threadIdx.x;
  if (t >= NS) return;
  int node = snodes[t];
  need2[node] = 1;
  need1[node] = 1;
  int s = row_ptr[node], e = row_ptr[node + 1];
  for (int j = s; j < e; ++j) need2[pairs[j].x] = 1;
}

__global__ void k_mark2(const int* __restrict__ row_ptr, const int2* __restrict__ pairs,
                        const int* __restrict__ need2, int* __restrict__ need1) {
  int n = blockIdx.x * blockDim.x + threadIdx.x;
  if (n >= NN || !need2[n]) return;
  int s = row_ptr[n], e = row_ptr[n + 1];
  for (int j = s; j < e; ++j) need1[pairs[j].x] = 1;
}

// ---------------- flag compaction: ballot + block scan, one atomic per block ----------------
__global__ void k_compact(const int* __restrict__ flags, int* __restrict__ list,
                          int* __restrict__ gcount) {
  __shared__ int wbase[4];
  int i = blockIdx.x * 256 + threadIdx.x;
  int f = (i < NN) ? flags[i] : 0;
  unsigned long long m = __ballot(f != 0);
  int lane = threadIdx.x & 63;
  int wv = threadIdx.x >> 6;
  int before = __popcll(m & ((1ull << lane) - 1ull));
  if (lane == 0) wbase[wv] = __popcll(m);
  __syncthreads();
  if (threadIdx.x == 0) {
    int c0 = wbase[0], c1 = wbase[1], c2 = wbase[2], c3 = wbase[3];
    int b0 = atomicAdd(gcount, c0 + c1 + c2 + c3);
    wbase[0] = b0;
    wbase[1] = b0 + c0;
    wbase[2] = b0 + c0 + c1;
    wbase[3] = b0 + c0 + c1 + c2;
  }
  __syncthreads();
  if (f) list[wbase[wv] + before] = i;
}

// ---------------- propagation: 16-lane group per listed node ----------------
// lane: group g = lane>>4 (node slot), c = lane&15 (float4 chunk of the row).
// Slots 0..7 of each tile live in lanes g*16+k; no cross-lane reduce needed.
template <int L0, int BYPOS>
__global__ void k_propg(const float4* __restrict__ U4, const float4* __restrict__ V4,
                        const float4* __restrict__ E4in, float4* __restrict__ E4out,
                        const int* __restrict__ row_ptr, const int2* __restrict__ pairs,
                        const int* __restrict__ list, const int* __restrict__ countp,
                        int cconst) {
  int n = cconst ? cconst : *countp;
  int lane = threadIdx.x & 63;
  int c = lane & 15;
  int sl = c & 7;
  int gstride = (gridDim.x * blockDim.x) >> 4;
  for (int gid = (blockIdx.x * blockDim.x + threadIdx.x) >> 4; gid < n; gid += gstride) {
    int node = list[gid];
    int start = row_ptr[node], end = row_ptr[node + 1];
    float4 acc = make_float4(0.f, 0.f, 0.f, 0.f);
    for (int t0 = start; t0 < end; t0 += 8) {
      int cap = end - t0;
      if (cap > 8) cap = 8;
      int2 mp = pairs[t0 + (sl < cap ? sl : 0)];  // coalesced tile-index load
      float4 r[8];
      float vv[8];
#pragma unroll
      for (int k = 0; k < 8; ++k) {
        int srclane = (lane & 48) + k;
        int s = __shfl(mp.x, srclane);
        float v = __int_as_float(__shfl(mp.y, srclane));
        vv[k] = (k < cap) ? v : 0.f;
        const float4* base;
        if (L0) {
          base = (s < NU) ? (U4 + (size_t)s * 16) : (V4 + (size_t)(s - NU) * 16);
        } else {
          base = E4in + (size_t)s * 16;
        }
        r[k] = base[c];  // 8 independent gathers in flight
      }
#pragma unroll
      for (int k = 0; k < 8; ++k) {
        acc.x += vv[k] * r[k].x;
        acc.y += vv[k] * r[k].y;
        acc.z += vv[k] * r[k].z;
        acc.w += vv[k] * r[k].w;
      }
    }
    size_t op = BYPOS ? (size_t)gid : (size_t)node;
    E4out[op * 16 + c] = acc;
  }
}

// gather sampled nodes for one layer into Es[l] (NS x 64). L0: virtual concat of U/V.
template <int L0>
__global__ void k_gather(const float4* __restrict__ U4, const float4* __restrict__ V4,
                         const float4* __restrict__ E4, float4* __restrict__ Es_l,
                         const int* __restrict__ snodes) {
  int t = blockIdx.x * blockDim.x + threadIdx.x;
  if (t >= NS * 16) return;
  int p = t >> 4, q = t & 15;
  int node = snodes[p];
  float4 r;
  if (L0) {
    r = (node < NU) ? U4[(size_t)node * 16 + q] : V4[(size_t)(node - NU) * 16 + q];
  } else {
    r = E4[(size_t)node * 16 + q];
  }
  Es_l[p * 16 + q] = r;
}

// ---------------- attention precompute: Mt[h][b][j] = (Wk_h Wq_h^T)[j][b], P[h][d][j] ----------------
__global__ void k_prep(const float* __restrict__ Wq, const float* __restrict__ Wk,
                       const float* __restrict__ Wv, const float* __restrict__ Wo,
                       float* __restrict__ Mt, float* __restrict__ P) {
  int t = blockIdx.x * 256 + threadIdx.x;
  if (t >= 16384) return;
  if (t < 8192) {
    int h = t >> 12;
    int b = (t >> 6) & 63;
    int j = t & 63;
    float s = 0.f;
    for (int k = 0; k < 32; ++k) s += Wk[j * 64 + h * 32 + k] * Wq[b * 64 + h * 32 + k];
    Mt[h * 4096 + b * 64 + j] = s;
  } else {
    int t2 = t - 8192;
    int h = t2 >> 12;
    int d = (t2 >> 6) & 63;
    int j = t2 & 63;
    float s = 0.f;
    for (int v = 0; v < 32; ++v) s += Wv[d * 64 + h * 32 + v] * Wo[(h * 32 + v) * 64 + j];
    P[h * 4096 + d * 64 + j] = s;
  }
}

// ---------------- attention per node: wave per node, lane = dim ----------------
__global__ void k_attn2(const float* __restrict__ Es, const float* __restrict__ Mt,
                        const float* __restrict__ P, float* __restrict__ Eo) {
  __shared__ float sb[4][3 * 64];
  int wv = threadIdx.x >> 6, lane = threadIdx.x & 63;
  int p = blockIdx.x * 4 + wv;
  if (p >= NS) return;
  const float inv_scale = 0.17677669529663687f;  // 1/sqrt(32)

  float e0 = Es[(size_t)0 * NS * DD + p * DD + lane];
  float e1 = Es[(size_t)1 * NS * DD + p * DD + lane];
  float e2 = Es[(size_t)2 * NS * DD + p * DD + lane];
  float e3 = Es[(size_t)3 * NS * DD + p * DD + lane];
  sb[wv][lane] = e0;

  const float* M0 = Mt;
  const float* M1 = Mt + 4096;
  float g0 = 0.f, g1 = 0.f;
#pragma unroll 8
  for (int b = 0; b < 64; ++b) {
    float eb = sb[wv][b];
    g0 = fmaf(M0[b * 64 + lane], eb, g0);
    g1 = fmaf(M1[b * 64 + lane], eb, g1);
  }

  float el[4] = {e0, e1, e2, e3};
  float sc[4][2];
#pragma unroll
  for (int l = 0; l < 4; ++l) {
    float p0 = el[l] * g0, p1 = el[l] * g1;
#pragma unroll
    for (int o = 32; o; o >>= 1) {
      p0 += __shfl_xor(p0, o);
      p1 += __shfl_xor(p1, o);
    }
    sc[l][0] = p0 * inv_scale;
    sc[l][1] = p1 * inv_scale;
  }

  float ebar[2];
#pragma unroll
  for (int h = 0; h < 2; ++h) {
    float m = fmaxf(fmaxf(sc[0][h], sc[1][h]), fmaxf(sc[2][h], sc[3][h]));
    float x0 = expf(sc[0][h] - m), x1 = expf(sc[1][h] - m);
    float x2 = expf(sc[2][h] - m), x3 = expf(sc[3][h] - m);
    float inv = 1.f / (x0 + x1 + x2 + x3);
    ebar[h] = (x0 * e0 + x1 * e1 + x2 * e2 + x3 * e3) * inv;
  }
  sb[wv][64 + lane] = ebar[0];
  sb[wv][128 + lane] = ebar[1];

  const float* P0 = P;
  const float* P1 = P + 4096;
  float o = 0.f;
#pragma unroll 8
  for (int d = 0; d < 64; ++d) {
    float b0 = sb[wv][64 + d];
    float b1 = sb[wv][128 + d];
    o = fmaf(P0[d * 64 + lane], b0, o);
    o = fmaf(P1[d * 64 + lane], b1, o);
  }
  Eo[(size_t)p * DD + lane] = o;
}

// final pair scoring
__global__ void k_dot(const float* __restrict__ Eo, float* __restrict__ out) {
  int w = (blockIdx.x * blockDim.x + threadIdx.x) >> 6;
  int lane = threadIdx.x & 63;
  if (w >= BB) return;
  float pd = Eo[(size_t)w * DD + lane] * Eo[(size_t)(BB + w) * DD + lane];
#pragma unroll
  for (int o = 32; o; o >>= 1) pd += __shfl_xor(pd, o);
  if (lane == 0) out[w] = pd;
}

extern "C" void kernel_launch(void* const* d_in, const int* in_sizes, int n_in,
                              void* d_out, int out_size, void* d_ws, size_t ws_size,
                              hipStream_t stream) {
  const int* edge_src = (const int*)d_in[0];
  const int* edge_dst = (const int*)d_in[1];
  const float* edge_val = (const float*)d_in[2];
  const float* U_emb = (const float*)d_in[3];
  const float* V_emb = (const float*)d_in[4];
  const float* Wq = (const float*)d_in[5];
  const float* Wk = (const float*)d_in[6];
  const float* Wv = (const float*)d_in[7];
  const float* Wo = (const float*)d_in[8];
  const int* u = (const int*)d_in[9];
  const int* ii = (const int*)d_in[10];
  float* out = (float*)d_out;

  const float4* U4 = (const float4*)U_emb;
  const float4* V4 = (const float4*)V_emb;

  // workspace layout (16B-aligned base)
  float* Ea = (float*)d_ws;                          // NN*64  (E1; coarse scratch sv before)
  float* Eb = Ea + (size_t)NN * DD;                  // NN*64  (E2; coarse scratch dst before)
  float* Es = Eb + (size_t)NN * DD;                  // 4*NS*64
  float* Eo = Es + (size_t)4 * NS * DD;              // NS*64
  float* Mt = Eo + (size_t)NS * DD;                  // 2*4096
  float* Pm = Mt + 8192;                             // 2*4096
  int* row_ptr = (int*)(Pm + 8192);                  // NN+1
  int* need1 = row_ptr + NN + 1;                     // NN
  int* need2 = need1 + NN;                           // NN
  int* bcount = need2 + NN;                          // NB
  int* bbase = bcount + NB;                          // NB+1
  int* bcur = bbase + NB + 1;                        // NB
  int* snodes = bcur + NB;                           // NS
  int* cnt1 = snodes + NS;                           // 1
  int* cnt2 = cnt1 + 1;                              // 1
  uintptr_t pa = (uintptr_t)(cnt2 + 1);
  pa = (pa + 15) & ~(uintptr_t)15;
  int2* pairs = (int2*)pa;                           // NE int2

  int2* c_sv = (int2*)Ea;   // NE int2 (10.2MB) — dead before E1 write
  int* c_dst = (int*)Eb;    // NE int  (5.1MB)  — dead before E2 write
  // node lists live in the Es[3] quarter (written only by the L3 prop, after lists are dead)
  int* n1list = (int*)(Es + (size_t)3 * NS * DD);    // <= NN ints
  int* n2list = n1list + NN;                         // <= NN ints (400k ints < 524k slot)

  float4* Ea4 = (float4*)Ea;
  float4* Eb4 = (float4*)Eb;
  float4* Es4 = (float4*)Es;

  // attention weight precompute + sample list (independent of graph work)
  k_prep<<<64, 256, 0, stream>>>(Wq, Wk, Wv, Wo, Mt, Pm);
  k_build_s<<<(NS + 255) / 256, 256, 0, stream>>>(u, ii, snodes);

  // CSR build: bucket hist -> bucket scan -> coarse bin -> fine place (+row_ptr)
  hipMemsetAsync(bcount, 0, NB * sizeof(int), stream);
  hipMemsetAsync(need1, 0, 2 * NN * sizeof(int), stream);
  hipMemsetAsync(cnt1, 0, 2 * sizeof(int), stream);
  int cgrid = (NE + CHUNK - 1) / CHUNK;
  k_bhist<<<cgrid, 256, 0, stream>>>(edge_dst, bcount);
  k_bscan<<<1, 1024, 0, stream>>>(bcount, bbase, bcur, row_ptr);
  k_coarse<<<cgrid, 256, 0, stream>>>(edge_src, edge_dst, edge_val, bcur, c_sv, c_dst);
  k_fine2<<<NB, 256, 0, stream>>>(bbase, c_sv, c_dst, pairs, row_ptr);

  // frontier marking + compaction
  k_mark_s<<<(NS + 255) / 256, 256, 0, stream>>>(snodes, row_ptr, pairs, need1, need2);
  k_mark2<<<(NN + 255) / 256, 256, 0, stream>>>(row_ptr, pairs, need2, need1);
  k_compact<<<(NN + 255) / 256, 256, 0, stream>>>(need1, n1list, cnt1);
  k_compact<<<(NN + 255) / 256, 256, 0, stream>>>(need2, n2list, cnt2);

  int ggrid = (NS * 16 + 255) / 256;

  k_gather<1><<<ggrid, 256, 0, stream>>>(U4, V4, nullptr, Es4 + (size_t)0 * NS * 16, snodes);
  k_propg<1, 0><<<2048, 256, 0, stream>>>(U4, V4, nullptr, Ea4, row_ptr, pairs, n1list, cnt1, 0);
  k_gather<0><<<ggrid, 256, 0, stream>>>(nullptr, nullptr, Ea4, Es4 + (size_t)1 * NS * 16, snodes);
  k_propg<0, 0><<<2048, 256, 0, stream>>>(nullptr, nullptr, Ea4, Eb4, row_ptr, pairs, n2list,
                                          cnt2, 0);
  k_gather<0><<<ggrid, 256, 0, stream>>>(nullptr, nullptr, Eb4, Es4 + (size_t)2 * NS * 16, snodes);
  k_propg<0, 1><<<512, 256, 0, stream>>>(nullptr, nullptr, Eb4, Es4 + (size_t)3 * NS * 16, row_ptr,
                                         pairs, snodes, nullptr, NS);

  k_attn2<<<(NS + 3) / 4, 256, 0, stream>>>(Es, Mt, Pm, Eo);
  k_dot<<<(BB * 64 + 255) / 256, 256, 0, stream>>>(Eo, out);
}

// Round 7
// 200.183 us; speedup vs baseline: 1.1429x; 1.1429x over previous
//
#include <hip/hip_runtime.h>

#define NU 120000
#define NI 80000
#define NN 200000
#define DD 64
#define NE 1280000
#define BB 4096
#define NS 8192    // 2*B sampled nodes
#define NB2 196    // ceil(NN/1024) buckets, bucket = dst>>10
#define BCAP 8192  // slack capacity per bucket segment (mean 6530, +20 sigma)
#define CH2 4096   // coarse chunk

// ---------------- init bucket cursors to segment bases ----------------
__global__ void k_init2(int* __restrict__ bcur) {
  int b = threadIdx.x;
  if (b < NB2) bcur[b] = b * BCAP;
}

// ---------------- coarse: LDS counting-sort of 4096 edges into 196 buckets ----------------
__global__ void k_coarse2(const int* __restrict__ src, const int* __restrict__ dst,
                          const float* __restrict__ val, int* __restrict__ bcur,
                          int2* __restrict__ c_sv) {
  __shared__ int2 sv[CH2];             // 32KB sorted staging
  __shared__ unsigned char map8[CH2];  // slot -> bucket
  __shared__ int hist[256];
  __shared__ int lbase[256];
  __shared__ int gbase[256];
  __shared__ int s[256];
  int t = threadIdx.x;
  hist[t] = 0;
  __syncthreads();
  int e0 = blockIdx.x * CH2;
  int d_[16];
#pragma unroll
  for (int k = 0; k < 16; ++k) {
    int e = e0 + k * 256 + t;
    d_[k] = (e < NE) ? dst[e] : -1;
    if (d_[k] >= 0) atomicAdd(&hist[d_[k] >> 10], 1);
  }
  __syncthreads();
  int x = hist[t];
  s[t] = x;
  __syncthreads();
  for (int off = 1; off < 256; off <<= 1) {
    int v = (t >= off) ? s[t - off] : 0;
    __syncthreads();
    s[t] += v;
    __syncthreads();
  }
  int lb = s[t] - x;
  lbase[t] = lb;
  gbase[t] = (x && t < NB2) ? atomicAdd(&bcur[t], x) : 0;
  for (int k = lb; k < lb + x; ++k) map8[k] = (unsigned char)t;
  hist[t] = 0;  // reuse as in-block cursor
  __syncthreads();
#pragma unroll
  for (int k = 0; k < 16; ++k) {
    int e = e0 + k * 256 + t;
    if (d_[k] >= 0) {
      int b = d_[k] >> 10;
      int lp = lbase[b] + atomicAdd(&hist[b], 1);
      sv[lp] = make_int2(src[e] | ((d_[k] & 1023) << 18), __float_as_int(val[e]));
    }
  }
  __syncthreads();
  int nval = NE - e0;
  if (nval > CH2) nval = CH2;
  for (int sidx = t; sidx < nval; sidx += 256) {
    int b = map8[sidx];
    c_sv[(size_t)gbase[b] + sidx - lbase[b]] = sv[sidx];  // coalesced runs (~21 int2)
  }
}

// ---------------- tiny scan of true bucket counts -> sbase; row_ptr[NN] ----------------
__global__ void k_scan_seg(const int* __restrict__ bcur, int* __restrict__ sbase,
                           int* __restrict__ row_ptr) {
  __shared__ int s[256];
  int t = threadIdx.x;
  int x = (t < NB2) ? (bcur[t] - t * BCAP) : 0;
  s[t] = x;
  __syncthreads();
  for (int off = 1; off < 256; off <<= 1) {
    int v = (t >= off) ? s[t - off] : 0;
    __syncthreads();
    s[t] += v;
    __syncthreads();
  }
  if (t < NB2) sbase[t] = s[t] - x;
  if (t == 0) row_ptr[NN] = NE;
}

// ---------------- fine: one block per bucket; per-node scan; writes row_ptr + pairs ----------------
__global__ void k_fine4(const int* __restrict__ bcur, const int* __restrict__ sbase,
                        const int2* __restrict__ c_sv, int2* __restrict__ pairs,
                        int* __restrict__ row_ptr) {
  __shared__ int cnt[1024];
  __shared__ int pre[1024];
  __shared__ int cur[1024];
  __shared__ int s[256];
  int b = blockIdx.x, t = threadIdx.x;
  int seg0 = b * BCAP;
  int segN = bcur[b] - seg0;
  int out0 = sbase[b];
  for (int k = t; k < 1024; k += 256) cnt[k] = 0;
  __syncthreads();
  for (int e = t; e < segN; e += 256) atomicAdd(&cnt[(c_sv[seg0 + e].x >> 18) & 1023], 1);
  __syncthreads();
  int a0 = cnt[4 * t], a1 = cnt[4 * t + 1], a2 = cnt[4 * t + 2], a3 = cnt[4 * t + 3];
  int tot = a0 + a1 + a2 + a3;
  s[t] = tot;
  __syncthreads();
  for (int off = 1; off < 256; off <<= 1) {
    int v = (t >= off) ? s[t - off] : 0;
    __syncthreads();
    s[t] += v;
    __syncthreads();
  }
  int base = s[t] - tot;
  pre[4 * t] = base;
  pre[4 * t + 1] = base + a0;
  pre[4 * t + 2] = base + a0 + a1;
  pre[4 * t + 3] = base + a0 + a1 + a2;
  int node0 = b << 10;
#pragma unroll
  for (int k = 0; k < 4; ++k) {
    int n = node0 + 4 * t + k;
    if (n < NN) row_ptr[n] = out0 + pre[4 * t + k];
  }
  for (int k = t; k < 1024; k += 256) cur[k] = 0;
  __syncthreads();
  for (int e = t; e < segN; e += 256) {
    int2 sv = c_sv[seg0 + e];
    int ld = (sv.x >> 18) & 1023;
    int off = atomicAdd(&cur[ld], 1);
    pairs[out0 + pre[ld] + off] = make_int2(sv.x & 0x3FFFF, sv.y);
  }
}

// ---------------- sample node list ----------------
__global__ void k_build_s(const int* __restrict__ u, const int* __restrict__ ii,
                          int* __restrict__ snodes) {
  int t = blockIdx.x * 256 + threadIdx.x;
  if (t < NS) snodes[t] = (t < BB) ? u[t] : NU + ii[t - BB];
}

// ---------------- frontier marking ----------------
__global__ void k_mark_s(const int* __restrict__ snodes, const int* __restrict__ row_ptr,
                         const int2* __restrict__ pairs, int* __restrict__ need1,
                         int* __restrict__ need2) {
  int t = blockIdx.x * blockDim.x + threadIdx.x;
  if (t >= NS) return;
  int node = snodes[t];
  need2[node] = 1;
  need1[node] = 1;
  int s = row_ptr[node], e = row_ptr[node + 1];
  for (int j = s; j < e; ++j) need2[pairs[j].x] = 1;
}

__global__ void k_mark2(const int* __restrict__ row_ptr, const int2* __restrict__ pairs,
                        const int* __restrict__ need2, int* __restrict__ need1) {
  int n = blockIdx.x * blockDim.x + threadIdx.x;
  if (n >= NN || !need2[n]) return;
  int s = row_ptr[n], e = row_ptr[n + 1];
  for (int j = s; j < e; ++j) need1[pairs[j].x] = 1;
}

// ---------------- flag compaction: ballot + block scan, one atomic per block ----------------
__global__ void k_compact(const int* __restrict__ flags, int* __restrict__ list,
                          int* __restrict__ gcount) {
  __shared__ int wbase[4];
  int i = blockIdx.x * 256 + threadIdx.x;
  int f = (i < NN) ? flags[i] : 0;
  unsigned long long m = __ballot(f != 0);
  int lane = threadIdx.x & 63;
  int wv = threadIdx.x >> 6;
  int before = __popcll(m & ((1ull << lane) - 1ull));
  if (lane == 0) wbase[wv] = __popcll(m);
  __syncthreads();
  if (threadIdx.x == 0) {
    int c0 = wbase[0], c1 = wbase[1], c2 = wbase[2], c3 = wbase[3];
    int b0 = atomicAdd(gcount, c0 + c1 + c2 + c3);
    wbase[0] = b0;
    wbase[1] = b0 + c0;
    wbase[2] = b0 + c0 + c1;
    wbase[3] = b0 + c0 + c1 + c2;
  }
  __syncthreads();
  if (f) list[wbase[wv] + before] = i;
}

// ---------------- propagation: 16-lane group per listed node ----------------
template <int L0, int BYPOS>
__global__ void k_propg(const float4* __restrict__ U4, const float4* __restrict__ V4,
                        const float4* __restrict__ E4in, float4* __restrict__ E4out,
                        const int* __restrict__ row_ptr, const int2* __restrict__ pairs,
                        const int* __restrict__ list, const int* __restrict__ countp,
                        int cconst) {
  int n = cconst ? cconst : *countp;
  int lane = threadIdx.x & 63;
  int c = lane & 15;
  int sl = c & 7;
  int gstride = (gridDim.x * blockDim.x) >> 4;
  for (int gid = (blockIdx.x * blockDim.x + threadIdx.x) >> 4; gid < n; gid += gstride) {
    int node = list[gid];
    int start = row_ptr[node], end = row_ptr[node + 1];
    float4 acc = make_float4(0.f, 0.f, 0.f, 0.f);
    for (int t0 = start; t0 < end; t0 += 8) {
      int cap = end - t0;
      if (cap > 8) cap = 8;
      int2 mp = pairs[t0 + (sl < cap ? sl : 0)];  // coalesced tile-index load
      float4 r[8];
      float vv[8];
#pragma unroll
      for (int k = 0; k < 8; ++k) {
        int srclane = (lane & 48) + k;
        int s = __shfl(mp.x, srclane);
        float v = __int_as_float(__shfl(mp.y, srclane));
        vv[k] = (k < cap) ? v : 0.f;
        const float4* base;
        if (L0) {
          base = (s < NU) ? (U4 + (size_t)s * 16) : (V4 + (size_t)(s - NU) * 16);
        } else {
          base = E4in + (size_t)s * 16;
        }
        r[k] = base[c];  // 8 independent gathers in flight
      }
#pragma unroll
      for (int k = 0; k < 8; ++k) {
        acc.x += vv[k] * r[k].x;
        acc.y += vv[k] * r[k].y;
        acc.z += vv[k] * r[k].z;
        acc.w += vv[k] * r[k].w;
      }
    }
    size_t op = BYPOS ? (size_t)gid : (size_t)node;
    E4out[op * 16 + c] = acc;
  }
}

// gather sampled nodes for one layer into Es[l] (NS x 64). L0: virtual concat of U/V.
template <int L0>
__global__ void k_gather(const float4* __restrict__ U4, const float4* __restrict__ V4,
                         const float4* __restrict__ E4, float4* __restrict__ Es_l,
                         const int* __restrict__ snodes) {
  int t = blockIdx.x * blockDim.x + threadIdx.x;
  if (t >= NS * 16) return;
  int p = t >> 4, q = t & 15;
  int node = snodes[p];
  float4 r;
  if (L0) {
    r = (node < NU) ? U4[(size_t)node * 16 + q] : V4[(size_t)(node - NU) * 16 + q];
  } else {
    r = E4[(size_t)node * 16 + q];
  }
  Es_l[p * 16 + q] = r;
}

// ---------------- attention precompute: Mt[h][b][j] = (Wk_h Wq_h^T)[j][b], P[h][d][j] ----------------
__global__ void k_prep(const float* __restrict__ Wq, const float* __restrict__ Wk,
                       const float* __restrict__ Wv, const float* __restrict__ Wo,
                       float* __restrict__ Mt, float* __restrict__ P) {
  int t = blockIdx.x * 256 + threadIdx.x;
  if (t >= 16384) return;
  if (t < 8192) {
    int h = t >> 12;
    int b = (t >> 6) & 63;
    int j = t & 63;
    float s = 0.f;
    for (int k = 0; k < 32; ++k) s += Wk[j * 64 + h * 32 + k] * Wq[b * 64 + h * 32 + k];
    Mt[h * 4096 + b * 64 + j] = s;
  } else {
    int t2 = t - 8192;
    int h = t2 >> 12;
    int d = (t2 >> 6) & 63;
    int j = t2 & 63;
    float s = 0.f;
    for (int v = 0; v < 32; ++v) s += Wv[d * 64 + h * 32 + v] * Wo[(h * 32 + v) * 64 + j];
    P[h * 4096 + d * 64 + j] = s;
  }
}

// ---------------- attention per node: wave per node, lane = dim ----------------
__global__ void k_attn2(const float* __restrict__ Es, const float* __restrict__ Mt,
                        const float* __restrict__ P, float* __restrict__ Eo) {
  __shared__ float sb[4][3 * 64];
  int wv = threadIdx.x >> 6, lane = threadIdx.x & 63;
  int p = blockIdx.x * 4 + wv;
  if (p >= NS) return;
  const float inv_scale = 0.17677669529663687f;  // 1/sqrt(32)

  float e0 = Es[(size_t)0 * NS * DD + p * DD + lane];
  float e1 = Es[(size_t)1 * NS * DD + p * DD + lane];
  float e2 = Es[(size_t)2 * NS * DD + p * DD + lane];
  float e3 = Es[(size_t)3 * NS * DD + p * DD + lane];
  sb[wv][lane] = e0;

  const float* M0 = Mt;
  const float* M1 = Mt + 4096;
  float g0 = 0.f, g1 = 0.f;
#pragma unroll 8
  for (int b = 0; b < 64; ++b) {
    float eb = sb[wv][b];
    g0 = fmaf(M0[b * 64 + lane], eb, g0);
    g1 = fmaf(M1[b * 64 + lane], eb, g1);
  }

  float el[4] = {e0, e1, e2, e3};
  float sc[4][2];
#pragma unroll
  for (int l = 0; l < 4; ++l) {
    float p0 = el[l] * g0, p1 = el[l] * g1;
#pragma unroll
    for (int o = 32; o; o >>= 1) {
      p0 += __shfl_xor(p0, o);
      p1 += __shfl_xor(p1, o);
    }
    sc[l][0] = p0 * inv_scale;
    sc[l][1] = p1 * inv_scale;
  }

  float ebar[2];
#pragma unroll
  for (int h = 0; h < 2; ++h) {
    float m = fmaxf(fmaxf(sc[0][h], sc[1][h]), fmaxf(sc[2][h], sc[3][h]));
    float x0 = expf(sc[0][h] - m), x1 = expf(sc[1][h] - m);
    float x2 = expf(sc[2][h] - m), x3 = expf(sc[3][h] - m);
    float inv = 1.f / (x0 + x1 + x2 + x3);
    ebar[h] = (x0 * e0 + x1 * e1 + x2 * e2 + x3 * e3) * inv;
  }
  sb[wv][64 + lane] = ebar[0];
  sb[wv][128 + lane] = ebar[1];

  const float* P0 = P;
  const float* P1 = P + 4096;
  float o = 0.f;
#pragma unroll 8
  for (int d = 0; d < 64; ++d) {
    float b0 = sb[wv][64 + d];
    float b1 = sb[wv][128 + d];
    o = fmaf(P0[d * 64 + lane], b0, o);
    o = fmaf(P1[d * 64 + lane], b1, o);
  }
  Eo[(size_t)p * DD + lane] = o;
}

// final pair scoring
__global__ void k_dot(const float* __restrict__ Eo, float* __restrict__ out) {
  int w = (blockIdx.x * blockDim.x + threadIdx.x) >> 6;
  int lane = threadIdx.x & 63;
  if (w >= BB) return;
  float pd = Eo[(size_t)w * DD + lane] * Eo[(size_t)(BB + w) * DD + lane];
#pragma unroll
  for (int o = 32; o; o >>= 1) pd += __shfl_xor(pd, o);
  if (lane == 0) out[w] = pd;
}

extern "C" void kernel_launch(void* const* d_in, const int* in_sizes, int n_in,
                              void* d_out, int out_size, void* d_ws, size_t ws_size,
                              hipStream_t stream) {
  const int* edge_src = (const int*)d_in[0];
  const int* edge_dst = (const int*)d_in[1];
  const float* edge_val = (const float*)d_in[2];
  const float* U_emb = (const float*)d_in[3];
  const float* V_emb = (const float*)d_in[4];
  const float* Wq = (const float*)d_in[5];
  const float* Wk = (const float*)d_in[6];
  const float* Wv = (const float*)d_in[7];
  const float* Wo = (const float*)d_in[8];
  const int* u = (const int*)d_in[9];
  const int* ii = (const int*)d_in[10];
  float* out = (float*)d_out;

  const float4* U4 = (const float4*)U_emb;
  const float4* V4 = (const float4*)V_emb;

  // workspace layout (16B-aligned base)
  float* Ea = (float*)d_ws;                          // NN*64  (E1; coarse segment scratch before)
  float* Eb = Ea + (size_t)NN * DD;                  // NN*64  (E2)
  float* Es = Eb + (size_t)NN * DD;                  // 4*NS*64
  float* Eo = Es + (size_t)4 * NS * DD;              // NS*64
  float* Mt = Eo + (size_t)NS * DD;                  // 2*4096
  float* Pm = Mt + 8192;                             // 2*4096
  int* row_ptr = (int*)(Pm + 8192);                  // NN+1
  int* need1 = row_ptr + NN + 1;                     // NN
  int* need2 = need1 + NN;                           // NN
  int* bcur = need2 + NN;                            // NB2
  int* sbase = bcur + NB2;                           // NB2
  int* snodes = sbase + NB2;                         // NS
  int* cnt1 = snodes + NS;                           // 1
  int* cnt2 = cnt1 + 1;                              // 1
  uintptr_t pa = (uintptr_t)(cnt2 + 1);
  pa = (pa + 15) & ~(uintptr_t)15;
  int2* pairs = (int2*)pa;                           // NE int2

  int2* c_sv = (int2*)Ea;  // NB2*BCAP int2 (12.8MB) — dead before E1 write
  // node lists live in the Es[3] quarter (written only by the L3 prop, after lists are dead)
  int* n1list = (int*)(Es + (size_t)3 * NS * DD);    // <= NN ints
  int* n2list = n1list + NN;                         // <= NN ints

  float4* Ea4 = (float4*)Ea;
  float4* Eb4 = (float4*)Eb;
  float4* Es4 = (float4*)Es;

  // attention weight precompute + sample list (independent of graph work)
  k_prep<<<64, 256, 0, stream>>>(Wq, Wk, Wv, Wo, Mt, Pm);
  k_build_s<<<(NS + 255) / 256, 256, 0, stream>>>(u, ii, snodes);

  // CSR build: init cursors -> coarse LDS-sort bin -> tiny scan -> fine place (+row_ptr)
  hipMemsetAsync(need1, 0, 2 * NN * sizeof(int), stream);
  hipMemsetAsync(cnt1, 0, 2 * sizeof(int), stream);
  k_init2<<<1, 256, 0, stream>>>(bcur);
  k_coarse2<<<(NE + CH2 - 1) / CH2, 256, 0, stream>>>(edge_src, edge_dst, edge_val, bcur, c_sv);
  k_scan_seg<<<1, 256, 0, stream>>>(bcur, sbase, row_ptr);
  k_fine4<<<NB2, 256, 0, stream>>>(bcur, sbase, c_sv, pairs, row_ptr);

  // frontier marking + compaction
  k_mark_s<<<(NS + 255) / 256, 256, 0, stream>>>(snodes, row_ptr, pairs, need1, need2);
  k_mark2<<<(NN + 255) / 256, 256, 0, stream>>>(row_ptr, pairs, need2, need1);
  k_compact<<<(NN + 255) / 256, 256, 0, stream>>>(need1, n1list, cnt1);
  k_compact<<<(NN + 255) / 256, 256, 0, stream>>>(need2, n2list, cnt2);

  int ggrid = (NS * 16 + 255) / 256;

  k_gather<1><<<ggrid, 256, 0, stream>>>(U4, V4, nullptr, Es4 + (size_t)0 * NS * 16, snodes);
  k_propg<1, 0><<<2048, 256, 0, stream>>>(U4, V4, nullptr, Ea4, row_ptr, pairs, n1list, cnt1, 0);
  k_gather<0><<<ggrid, 256, 0, stream>>>(nullptr, nullptr, Ea4, Es4 + (size_t)1 * NS * 16, snodes);
  k_propg<0, 0><<<2048, 256, 0, stream>>>(nullptr, nullptr, Ea4, Eb4, row_ptr, pairs, n2list,
                                          cnt2, 0);
  k_gather<0><<<ggrid, 256, 0, stream>>>(nullptr, nullptr, Eb4, Es4 + (size_t)2 * NS * 16, snodes);
  k_propg<0, 1><<<512, 256, 0, stream>>>(nullptr, nullptr, Eb4, Es4 + (size_t)3 * NS * 16, row_ptr,
                                         pairs, snodes, nullptr, NS);

  k_attn2<<<(NS + 3) / 4, 256, 0, stream>>>(Es, Mt, Pm, Eo);
  k_dot<<<(BB * 64 + 255) / 256, 256, 0, stream>>>(Eo, out);
}

// Round 8
// 185.290 us; speedup vs baseline: 1.2348x; 1.0804x over previous
//
#include <hip/hip_runtime.h>
#include <hip/hip_fp16.h>

#define NU 120000
#define NI 80000
#define NN 200000
#define DD 64
#define NE 1280000
#define BB 4096
#define NS 8192    // 2*B sampled nodes
#define NB2 196    // ceil(NN/1024) buckets, bucket = dst>>10
#define BCAP 8192  // slack capacity per bucket segment (mean 6530, +20 sigma)
#define CH2 4096   // coarse chunk

// ---------------- init bucket cursors to segment bases ----------------
__global__ void k_init2(int* __restrict__ bcur) {
  int b = threadIdx.x;
  if (b < NB2) bcur[b] = b * BCAP;
}

// ---------------- coarse: LDS counting-sort of 4096 edges into 196 buckets ----------------
__global__ void k_coarse2(const int* __restrict__ src, const int* __restrict__ dst,
                          const float* __restrict__ val, int* __restrict__ bcur,
                          int2* __restrict__ c_sv) {
  __shared__ int2 sv[CH2];             // 32KB sorted staging
  __shared__ unsigned char map8[CH2];  // slot -> bucket
  __shared__ int hist[256];
  __shared__ int lbase[256];
  __shared__ int gbase[256];
  __shared__ int s[256];
  int t = threadIdx.x;
  hist[t] = 0;
  __syncthreads();
  int e0 = blockIdx.x * CH2;
  int d_[16];
#pragma unroll
  for (int k = 0; k < 16; ++k) {
    int e = e0 + k * 256 + t;
    d_[k] = (e < NE) ? dst[e] : -1;
    if (d_[k] >= 0) atomicAdd(&hist[d_[k] >> 10], 1);
  }
  __syncthreads();
  int x = hist[t];
  s[t] = x;
  __syncthreads();
  for (int off = 1; off < 256; off <<= 1) {
    int v = (t >= off) ? s[t - off] : 0;
    __syncthreads();
    s[t] += v;
    __syncthreads();
  }
  int lb = s[t] - x;
  lbase[t] = lb;
  gbase[t] = (x && t < NB2) ? atomicAdd(&bcur[t], x) : 0;
  for (int k = lb; k < lb + x; ++k) map8[k] = (unsigned char)t;
  hist[t] = 0;  // reuse as in-block cursor
  __syncthreads();
#pragma unroll
  for (int k = 0; k < 16; ++k) {
    int e = e0 + k * 256 + t;
    if (d_[k] >= 0) {
      int b = d_[k] >> 10;
      int lp = lbase[b] + atomicAdd(&hist[b], 1);
      sv[lp] = make_int2(src[e] | ((d_[k] & 1023) << 18), __float_as_int(val[e]));
    }
  }
  __syncthreads();
  int nval = NE - e0;
  if (nval > CH2) nval = CH2;
  for (int sidx = t; sidx < nval; sidx += 256) {
    int b = map8[sidx];
    c_sv[(size_t)gbase[b] + sidx - lbase[b]] = sv[sidx];  // coalesced runs
  }
}

// ---------------- tiny scan of true bucket counts -> sbase; row_ptr[NN] ----------------
__global__ void k_scan_seg(const int* __restrict__ bcur, int* __restrict__ sbase,
                           int* __restrict__ row_ptr) {
  __shared__ int s[256];
  int t = threadIdx.x;
  int x = (t < NB2) ? (bcur[t] - t * BCAP) : 0;
  s[t] = x;
  __syncthreads();
  for (int off = 1; off < 256; off <<= 1) {
    int v = (t >= off) ? s[t - off] : 0;
    __syncthreads();
    s[t] += v;
    __syncthreads();
  }
  if (t < NB2) sbase[t] = s[t] - x;
  if (t == 0) row_ptr[NN] = NE;
}

// ---------------- fine: one block per bucket; per-node scan; writes row_ptr + pairs ----------------
__global__ void k_fine4(const int* __restrict__ bcur, const int* __restrict__ sbase,
                        const int2* __restrict__ c_sv, int2* __restrict__ pairs,
                        int* __restrict__ row_ptr) {
  __shared__ int cnt[1024];
  __shared__ int pre[1024];
  __shared__ int cur[1024];
  __shared__ int s[256];
  int b = blockIdx.x, t = threadIdx.x;
  int seg0 = b * BCAP;
  int segN = bcur[b] - seg0;
  int out0 = sbase[b];
  for (int k = t; k < 1024; k += 256) cnt[k] = 0;
  __syncthreads();
  for (int e = t; e < segN; e += 256) atomicAdd(&cnt[(c_sv[seg0 + e].x >> 18) & 1023], 1);
  __syncthreads();
  int a0 = cnt[4 * t], a1 = cnt[4 * t + 1], a2 = cnt[4 * t + 2], a3 = cnt[4 * t + 3];
  int tot = a0 + a1 + a2 + a3;
  s[t] = tot;
  __syncthreads();
  for (int off = 1; off < 256; off <<= 1) {
    int v = (t >= off) ? s[t - off] : 0;
    __syncthreads();
    s[t] += v;
    __syncthreads();
  }
  int base = s[t] - tot;
  pre[4 * t] = base;
  pre[4 * t + 1] = base + a0;
  pre[4 * t + 2] = base + a0 + a1;
  pre[4 * t + 3] = base + a0 + a1 + a2;
  int node0 = b << 10;
#pragma unroll
  for (int k = 0; k < 4; ++k) {
    int n = node0 + 4 * t + k;
    if (n < NN) row_ptr[n] = out0 + pre[4 * t + k];
  }
  for (int k = t; k < 1024; k += 256) cur[k] = 0;
  __syncthreads();
  for (int e = t; e < segN; e += 256) {
    int2 sv = c_sv[seg0 + e];
    int ld = (sv.x >> 18) & 1023;
    int off = atomicAdd(&cur[ld], 1);
    pairs[out0 + pre[ld] + off] = make_int2(sv.x & 0x3FFFF, sv.y);
  }
}

// ---------------- sample node list ----------------
__global__ void k_build_s(const int* __restrict__ u, const int* __restrict__ ii,
                          int* __restrict__ snodes) {
  int t = blockIdx.x * 256 + threadIdx.x;
  if (t < NS) snodes[t] = (t < BB) ? u[t] : NU + ii[t - BB];
}

// ---------------- fp32 U||V -> fp16 table H0 ----------------
__global__ void k_conv(const float4* __restrict__ U4, const float4* __restrict__ V4,
                       uint2* __restrict__ H0) {
  int t = blockIdx.x * 256 + threadIdx.x;
  if (t >= NN * 16) return;
  int node = t >> 4, q = t & 15;
  float4 r = (node < NU) ? U4[(size_t)node * 16 + q] : V4[(size_t)(node - NU) * 16 + q];
  __half2 a = __floats2half2_rn(r.x, r.y);
  __half2 b = __floats2half2_rn(r.z, r.w);
  uint2 o;
  o.x = __builtin_bit_cast(unsigned int, a);
  o.y = __builtin_bit_cast(unsigned int, b);
  H0[(size_t)node * 16 + q] = o;
}

// ---------------- frontier marking ----------------
__global__ void k_mark_s(const int* __restrict__ snodes, const int* __restrict__ row_ptr,
                         const int2* __restrict__ pairs, int* __restrict__ need1,
                         int* __restrict__ need2) {
  int t = blockIdx.x * blockDim.x + threadIdx.x;
  if (t >= NS) return;
  int node = snodes[t];
  need2[node] = 1;
  need1[node] = 1;
  int s = row_ptr[node], e = row_ptr[node + 1];
  for (int j = s; j < e; ++j) need2[pairs[j].x] = 1;
}

__global__ void k_mark2(const int* __restrict__ row_ptr, const int2* __restrict__ pairs,
                        const int* __restrict__ need2, int* __restrict__ need1) {
  int n = blockIdx.x * blockDim.x + threadIdx.x;
  if (n >= NN || !need2[n]) return;
  int s = row_ptr[n], e = row_ptr[n + 1];
  for (int j = s; j < e; ++j) need1[pairs[j].x] = 1;
}

// ---------------- flag compaction: ballot + block scan, one atomic per block ----------------
__global__ void k_compact(const int* __restrict__ flags, int* __restrict__ list,
                          int* __restrict__ gcount) {
  __shared__ int wbase[4];
  int i = blockIdx.x * 256 + threadIdx.x;
  int f = (i < NN) ? flags[i] : 0;
  unsigned long long m = __ballot(f != 0);
  int lane = threadIdx.x & 63;
  int wv = threadIdx.x >> 6;
  int before = __popcll(m & ((1ull << lane) - 1ull));
  if (lane == 0) wbase[wv] = __popcll(m);
  __syncthreads();
  if (threadIdx.x == 0) {
    int c0 = wbase[0], c1 = wbase[1], c2 = wbase[2], c3 = wbase[3];
    int b0 = atomicAdd(gcount, c0 + c1 + c2 + c3);
    wbase[0] = b0;
    wbase[1] = b0 + c0;
    wbase[2] = b0 + c0 + c1;
    wbase[3] = b0 + c0 + c1 + c2;
  }
  __syncthreads();
  if (f) list[wbase[wv] + before] = i;
}

// ---------------- propagation: 16-lane group per listed node, fp16 in, fp32 acc ----------------
// lane: group g = lane>>4, c = lane&15 (4-dim chunk = 8B of fp16 row), sl = c&7 (edge slot).
template <int BYPOS, int OUTF32>
__global__ void k_proph(const uint2* __restrict__ Hin, uint2* __restrict__ Hout,
                        float4* __restrict__ Fout, const int* __restrict__ row_ptr,
                        const int2* __restrict__ pairs, const int* __restrict__ list,
                        const int* __restrict__ countp, int cconst) {
  int n = cconst ? cconst : *countp;
  int lane = threadIdx.x & 63;
  int c = lane & 15;
  int sl = c & 7;
  int gstride = (gridDim.x * blockDim.x) >> 4;
  for (int gid = (blockIdx.x * blockDim.x + threadIdx.x) >> 4; gid < n; gid += gstride) {
    int node = list[gid];
    int start = row_ptr[node], end = row_ptr[node + 1];
    float4 acc = make_float4(0.f, 0.f, 0.f, 0.f);
    for (int t0 = start; t0 < end; t0 += 8) {
      int cap = end - t0;
      if (cap > 8) cap = 8;
      int2 mp = pairs[t0 + (sl < cap ? sl : 0)];  // coalesced tile-index load
      uint2 r[8];
      float vv[8];
#pragma unroll
      for (int k = 0; k < 8; ++k) {
        int srclane = (lane & 48) + k;
        int s = __shfl(mp.x, srclane);
        float v = __int_as_float(__shfl(mp.y, srclane));
        vv[k] = (k < cap) ? v : 0.f;
        r[k] = Hin[(size_t)s * 16 + c];  // 8 independent 8B gathers in flight
      }
#pragma unroll
      for (int k = 0; k < 8; ++k) {
        float2 f0 = __half22float2(__builtin_bit_cast(__half2, r[k].x));
        float2 f1 = __half22float2(__builtin_bit_cast(__half2, r[k].y));
        acc.x += vv[k] * f0.x;
        acc.y += vv[k] * f0.y;
        acc.z += vv[k] * f1.x;
        acc.w += vv[k] * f1.y;
      }
    }
    size_t op = BYPOS ? (size_t)gid : (size_t)node;
    if (OUTF32) {
      Fout[op * 16 + c] = acc;
    } else {
      __half2 a = __floats2half2_rn(acc.x, acc.y);
      __half2 b = __floats2half2_rn(acc.z, acc.w);
      uint2 o;
      o.x = __builtin_bit_cast(unsigned int, a);
      o.y = __builtin_bit_cast(unsigned int, b);
      Hout[op * 16 + c] = o;
    }
  }
}

// gather sampled nodes from fp32 U||V into Es[0]
__global__ void k_gather0(const float4* __restrict__ U4, const float4* __restrict__ V4,
                          float4* __restrict__ Es_l, const int* __restrict__ snodes) {
  int t = blockIdx.x * blockDim.x + threadIdx.x;
  if (t >= NS * 16) return;
  int p = t >> 4, q = t & 15;
  int node = snodes[p];
  Es_l[p * 16 + q] =
      (node < NU) ? U4[(size_t)node * 16 + q] : V4[(size_t)(node - NU) * 16 + q];
}

// gather sampled nodes from an fp16 table into Es[l] (fp32)
__global__ void k_gather_h(const uint2* __restrict__ Htab, float4* __restrict__ Es_l,
                           const int* __restrict__ snodes) {
  int t = blockIdx.x * blockDim.x + threadIdx.x;
  if (t >= NS * 16) return;
  int p = t >> 4, q = t & 15;
  int node = snodes[p];
  uint2 r = Htab[(size_t)node * 16 + q];
  float2 f0 = __half22float2(__builtin_bit_cast(__half2, r.x));
  float2 f1 = __half22float2(__builtin_bit_cast(__half2, r.y));
  Es_l[p * 16 + q] = make_float4(f0.x, f0.y, f1.x, f1.y);
}

// ---------------- attention precompute: Mt[h][b][j] = (Wk_h Wq_h^T)[j][b], P[h][d][j] ----------------
__global__ void k_prep(const float* __restrict__ Wq, const float* __restrict__ Wk,
                       const float* __restrict__ Wv, const float* __restrict__ Wo,
                       float* __restrict__ Mt, float* __restrict__ P) {
  int t = blockIdx.x * 256 + threadIdx.x;
  if (t >= 16384) return;
  if (t < 8192) {
    int h = t >> 12;
    int b = (t >> 6) & 63;
    int j = t & 63;
    float s = 0.f;
    for (int k = 0; k < 32; ++k) s += Wk[j * 64 + h * 32 + k] * Wq[b * 64 + h * 32 + k];
    Mt[h * 4096 + b * 64 + j] = s;
  } else {
    int t2 = t - 8192;
    int h = t2 >> 12;
    int d = (t2 >> 6) & 63;
    int j = t2 & 63;
    float s = 0.f;
    for (int v = 0; v < 32; ++v) s += Wv[d * 64 + h * 32 + v] * Wo[(h * 32 + v) * 64 + j];
    P[h * 4096 + d * 64 + j] = s;
  }
}

// ---------------- attention per node: wave per node, lane = dim ----------------
__global__ void k_attn2(const float* __restrict__ Es, const float* __restrict__ Mt,
                        const float* __restrict__ P, float* __restrict__ Eo) {
  __shared__ float sb[4][3 * 64];
  int wv = threadIdx.x >> 6, lane = threadIdx.x & 63;
  int p = blockIdx.x * 4 + wv;
  if (p >= NS) return;
  const float inv_scale = 0.17677669529663687f;  // 1/sqrt(32)

  float e0 = Es[(size_t)0 * NS * DD + p * DD + lane];
  float e1 = Es[(size_t)1 * NS * DD + p * DD + lane];
  float e2 = Es[(size_t)2 * NS * DD + p * DD + lane];
  float e3 = Es[(size_t)3 * NS * DD + p * DD + lane];
  sb[wv][lane] = e0;

  const float* M0 = Mt;
  const float* M1 = Mt + 4096;
  float g0 = 0.f, g1 = 0.f;
#pragma unroll 8
  for (int b = 0; b < 64; ++b) {
    float eb = sb[wv][b];
    g0 = fmaf(M0[b * 64 + lane], eb, g0);
    g1 = fmaf(M1[b * 64 + lane], eb, g1);
  }

  float el[4] = {e0, e1, e2, e3};
  float sc[4][2];
#pragma unroll
  for (int l = 0; l < 4; ++l) {
    float p0 = el[l] * g0, p1 = el[l] * g1;
#pragma unroll
    for (int o = 32; o; o >>= 1) {
      p0 += __shfl_xor(p0, o);
      p1 += __shfl_xor(p1, o);
    }
    sc[l][0] = p0 * inv_scale;
    sc[l][1] = p1 * inv_scale;
  }

  float ebar[2];
#pragma unroll
  for (int h = 0; h < 2; ++h) {
    float m = fmaxf(fmaxf(sc[0][h], sc[1][h]), fmaxf(sc[2][h], sc[3][h]));
    float x0 = expf(sc[0][h] - m), x1 = expf(sc[1][h] - m);
    float x2 = expf(sc[2][h] - m), x3 = expf(sc[3][h] - m);
    float inv = 1.f / (x0 + x1 + x2 + x3);
    ebar[h] = (x0 * e0 + x1 * e1 + x2 * e2 + x3 * e3) * inv;
  }
  sb[wv][64 + lane] = ebar[0];
  sb[wv][128 + lane] = ebar[1];

  const float* P0 = P;
  const float* P1 = P + 4096;
  float o = 0.f;
#pragma unroll 8
  for (int d = 0; d < 64; ++d) {
    float b0 = sb[wv][64 + d];
    float b1 = sb[wv][128 + d];
    o = fmaf(P0[d * 64 + lane], b0, o);
    o = fmaf(P1[d * 64 + lane], b1, o);
  }
  Eo[(size_t)p * DD + lane] = o;
}

// final pair scoring
__global__ void k_dot(const float* __restrict__ Eo, float* __restrict__ out) {
  int w = (blockIdx.x * blockDim.x + threadIdx.x) >> 6;
  int lane = threadIdx.x & 63;
  if (w >= BB) return;
  float pd = Eo[(size_t)w * DD + lane] * Eo[(size_t)(BB + w) * DD + lane];
#pragma unroll
  for (int o = 32; o; o >>= 1) pd += __shfl_xor(pd, o);
  if (lane == 0) out[w] = pd;
}

extern "C" void kernel_launch(void* const* d_in, const int* in_sizes, int n_in,
                              void* d_out, int out_size, void* d_ws, size_t ws_size,
                              hipStream_t stream) {
  const int* edge_src = (const int*)d_in[0];
  const int* edge_dst = (const int*)d_in[1];
  const float* edge_val = (const float*)d_in[2];
  const float* U_emb = (const float*)d_in[3];
  const float* V_emb = (const float*)d_in[4];
  const float* Wq = (const float*)d_in[5];
  const float* Wk = (const float*)d_in[6];
  const float* Wv = (const float*)d_in[7];
  const float* Wo = (const float*)d_in[8];
  const int* u = (const int*)d_in[9];
  const int* ii = (const int*)d_in[10];
  float* out = (float*)d_out;

  const float4* U4 = (const float4*)U_emb;
  const float4* V4 = (const float4*)V_emb;

  // workspace layout (16B-aligned base)
  float* Ea = (float*)d_ws;                          // 51.2MB region: H0 | H1 (fp16 tables)
  float* Eb = Ea + (size_t)NN * DD;                  // 51.2MB region: H2 (c_sv scratch before)
  float* Es = Eb + (size_t)NN * DD;                  // 4*NS*64 fp32
  float* Eo = Es + (size_t)4 * NS * DD;              // NS*64
  float* Mt = Eo + (size_t)NS * DD;                  // 2*4096
  float* Pm = Mt + 8192;                             // 2*4096
  int* row_ptr = (int*)(Pm + 8192);                  // NN+1
  int* need1 = row_ptr + NN + 1;                     // NN
  int* need2 = need1 + NN;                           // NN
  int* bcur = need2 + NN;                            // NB2
  int* sbase = bcur + NB2;                           // NB2
  int* snodes = sbase + NB2;                         // NS
  int* cnt1 = snodes + NS;                           // 1
  int* cnt2 = cnt1 + 1;                              // 1
  uintptr_t pa = (uintptr_t)(cnt2 + 1);
  pa = (pa + 15) & ~(uintptr_t)15;
  int2* pairs = (int2*)pa;                           // NE int2

  uint2* H0 = (uint2*)Ea;                 // NN*16 uint2 = 25.6MB
  uint2* H1 = H0 + (size_t)NN * 16;       // 25.6MB
  uint2* H2 = (uint2*)Eb;                 // 25.6MB (written after c_sv dead)
  int2* c_sv = (int2*)Eb;                 // NB2*BCAP int2 = 12.8MB — dead after k_fine4
  // node lists live in the Es[3] quarter (Es[3] written by L3 prop, after lists are dead)
  int* n1list = (int*)(Es + (size_t)3 * NS * DD);    // <= NN ints
  int* n2list = n1list + NN;                         // <= NN ints

  float4* Es4 = (float4*)Es;

  // attention weight precompute + sample list + fp16 E0 table (independent of CSR)
  k_prep<<<64, 256, 0, stream>>>(Wq, Wk, Wv, Wo, Mt, Pm);
  k_build_s<<<(NS + 255) / 256, 256, 0, stream>>>(u, ii, snodes);
  k_conv<<<(NN * 16 + 255) / 256, 256, 0, stream>>>(U4, V4, H0);

  // CSR build: init cursors -> coarse LDS-sort bin -> tiny scan -> fine place (+row_ptr)
  hipMemsetAsync(need1, 0, 2 * NN * sizeof(int), stream);
  hipMemsetAsync(cnt1, 0, 2 * sizeof(int), stream);
  k_init2<<<1, 256, 0, stream>>>(bcur);
  k_coarse2<<<(NE + CH2 - 1) / CH2, 256, 0, stream>>>(edge_src, edge_dst, edge_val, bcur, c_sv);
  k_scan_seg<<<1, 256, 0, stream>>>(bcur, sbase, row_ptr);
  k_fine4<<<NB2, 256, 0, stream>>>(bcur, sbase, c_sv, pairs, row_ptr);

  // frontier marking + compaction
  k_mark_s<<<(NS + 255) / 256, 256, 0, stream>>>(snodes, row_ptr, pairs, need1, need2);
  k_mark2<<<(NN + 255) / 256, 256, 0, stream>>>(row_ptr, pairs, need2, need1);
  k_compact<<<(NN + 255) / 256, 256, 0, stream>>>(need1, n1list, cnt1);
  k_compact<<<(NN + 255) / 256, 256, 0, stream>>>(need2, n2list, cnt2);

  int ggrid = (NS * 16 + 255) / 256;

  k_gather0<<<ggrid, 256, 0, stream>>>(U4, V4, Es4 + (size_t)0 * NS * 16, snodes);
  // E1 = A @ E0 at need1 (fp16 in, fp16 out)
  k_proph<0, 0><<<2048, 256, 0, stream>>>(H0, H1, nullptr, row_ptr, pairs, n1list, cnt1, 0);
  k_gather_h<<<ggrid, 256, 0, stream>>>(H1, Es4 + (size_t)1 * NS * 16, snodes);
  // E2 = A @ E1 at need2
  k_proph<0, 0><<<2048, 256, 0, stream>>>(H1, H2, nullptr, row_ptr, pairs, n2list, cnt2, 0);
  k_gather_h<<<ggrid, 256, 0, stream>>>(H2, Es4 + (size_t)2 * NS * 16, snodes);
  // E3 at sampled nodes only, fp32 straight into Es[3]
  k_proph<1, 1><<<512, 256, 0, stream>>>(H2, nullptr, Es4 + (size_t)3 * NS * 16, row_ptr, pairs,
                                         snodes, nullptr, NS);

  k_attn2<<<(NS + 3) / 4, 256, 0, stream>>>(Es, Mt, Pm, Eo);
  k_dot<<<(BB * 64 + 255) / 256, 256, 0, stream>>>(Eo, out);
}

// Round 9
// 181.183 us; speedup vs baseline: 1.2627x; 1.0227x over previous
//
#include <hip/hip_runtime.h>
#include <hip/hip_fp16.h>

#define NU 120000
#define NI 80000
#define NN 200000
#define DD 64
#define NE 1280000
#define BB 4096
#define NS 8192    // 2*B sampled nodes
#define NB2 196    // ceil(NN/1024) buckets, bucket = dst>>10
#define BCAP 8192  // slack capacity per bucket segment (mean 6530, +20 sigma)
#define CH2 4096   // coarse chunk

// ---------------- zero scratch flags/counters (replaces pathological hipMemsetAsync) ----------------
__global__ void k_zero(int4* __restrict__ needs, int* __restrict__ cnt) {
  int t = blockIdx.x * 256 + threadIdx.x;
  if (t < (2 * NN) / 4) needs[t] = make_int4(0, 0, 0, 0);
  if (t == 0) {
    cnt[0] = 0;
    cnt[1] = 0;
  }
}

// ---------------- init bucket cursors to segment bases ----------------
__global__ void k_init2(int* __restrict__ bcur) {
  int b = threadIdx.x;
  if (b < NB2) bcur[b] = b * BCAP;
}

// ---------------- coarse: LDS counting-sort of 4096 edges into 196 buckets ----------------
__global__ void k_coarse2(const int* __restrict__ src, const int* __restrict__ dst,
                          const float* __restrict__ val, int* __restrict__ bcur,
                          int2* __restrict__ c_sv) {
  __shared__ int2 sv[CH2];             // 32KB sorted staging
  __shared__ unsigned char map8[CH2];  // slot -> bucket
  __shared__ int hist[256];
  __shared__ int lbase[256];
  __shared__ int gbase[256];
  __shared__ int s[256];
  int t = threadIdx.x;
  hist[t] = 0;
  __syncthreads();
  int e0 = blockIdx.x * CH2;
  int d_[16];
#pragma unroll
  for (int k = 0; k < 16; ++k) {
    int e = e0 + k * 256 + t;
    d_[k] = (e < NE) ? dst[e] : -1;
    if (d_[k] >= 0) atomicAdd(&hist[d_[k] >> 10], 1);
  }
  __syncthreads();
  int x = hist[t];
  s[t] = x;
  __syncthreads();
  for (int off = 1; off < 256; off <<= 1) {
    int v = (t >= off) ? s[t - off] : 0;
    __syncthreads();
    s[t] += v;
    __syncthreads();
  }
  int lb = s[t] - x;
  lbase[t] = lb;
  gbase[t] = (x && t < NB2) ? atomicAdd(&bcur[t], x) : 0;
  for (int k = lb; k < lb + x; ++k) map8[k] = (unsigned char)t;
  hist[t] = 0;  // reuse as in-block cursor
  __syncthreads();
#pragma unroll
  for (int k = 0; k < 16; ++k) {
    int e = e0 + k * 256 + t;
    if (d_[k] >= 0) {
      int b = d_[k] >> 10;
      int lp = lbase[b] + atomicAdd(&hist[b], 1);
      sv[lp] = make_int2(src[e] | ((d_[k] & 1023) << 18), __float_as_int(val[e]));
    }
  }
  __syncthreads();
  int nval = NE - e0;
  if (nval > CH2) nval = CH2;
  for (int sidx = t; sidx < nval; sidx += 256) {
    int b = map8[sidx];
    c_sv[(size_t)gbase[b] + sidx - lbase[b]] = sv[sidx];  // coalesced runs
  }
}

// ---------------- tiny scan of true bucket counts -> sbase; row_ptr[NN] ----------------
__global__ void k_scan_seg(const int* __restrict__ bcur, int* __restrict__ sbase,
                           int* __restrict__ row_ptr) {
  __shared__ int s[256];
  int t = threadIdx.x;
  int x = (t < NB2) ? (bcur[t] - t * BCAP) : 0;
  s[t] = x;
  __syncthreads();
  for (int off = 1; off < 256; off <<= 1) {
    int v = (t >= off) ? s[t - off] : 0;
    __syncthreads();
    s[t] += v;
    __syncthreads();
  }
  if (t < NB2) sbase[t] = s[t] - x;
  if (t == 0) row_ptr[NN] = NE;
}

// ---------------- fine: one block per bucket; per-node scan; writes row_ptr + pairs ----------------
__global__ void k_fine4(const int* __restrict__ bcur, const int* __restrict__ sbase,
                        const int2* __restrict__ c_sv, int2* __restrict__ pairs,
                        int* __restrict__ row_ptr) {
  __shared__ int cnt[1024];
  __shared__ int pre[1024];
  __shared__ int cur[1024];
  __shared__ int s[256];
  int b = blockIdx.x, t = threadIdx.x;
  int seg0 = b * BCAP;
  int segN = bcur[b] - seg0;
  int out0 = sbase[b];
  for (int k = t; k < 1024; k += 256) cnt[k] = 0;
  __syncthreads();
  for (int e = t; e < segN; e += 256) atomicAdd(&cnt[(c_sv[seg0 + e].x >> 18) & 1023], 1);
  __syncthreads();
  int a0 = cnt[4 * t], a1 = cnt[4 * t + 1], a2 = cnt[4 * t + 2], a3 = cnt[4 * t + 3];
  int tot = a0 + a1 + a2 + a3;
  s[t] = tot;
  __syncthreads();
  for (int off = 1; off < 256; off <<= 1) {
    int v = (t >= off) ? s[t - off] : 0;
    __syncthreads();
    s[t] += v;
    __syncthreads();
  }
  int base = s[t] - tot;
  pre[4 * t] = base;
  pre[4 * t + 1] = base + a0;
  pre[4 * t + 2] = base + a0 + a1;
  pre[4 * t + 3] = base + a0 + a1 + a2;
  int node0 = b << 10;
#pragma unroll
  for (int k = 0; k < 4; ++k) {
    int n = node0 + 4 * t + k;
    if (n < NN) row_ptr[n] = out0 + pre[4 * t + k];
  }
  for (int k = t; k < 1024; k += 256) cur[k] = 0;
  __syncthreads();
  for (int e = t; e < segN; e += 256) {
    int2 sv = c_sv[seg0 + e];
    int ld = (sv.x >> 18) & 1023;
    int off = atomicAdd(&cur[ld], 1);
    pairs[out0 + pre[ld] + off] = make_int2(sv.x & 0x3FFFF, sv.y);
  }
}

// ---------------- sample node list ----------------
__global__ void k_build_s(const int* __restrict__ u, const int* __restrict__ ii,
                          int* __restrict__ snodes) {
  int t = blockIdx.x * 256 + threadIdx.x;
  if (t < NS) snodes[t] = (t < BB) ? u[t] : NU + ii[t - BB];
}

// ---------------- fp32 U||V -> fp16 table H0 ----------------
__global__ void k_conv(const float4* __restrict__ U4, const float4* __restrict__ V4,
                       uint2* __restrict__ H0) {
  int t = blockIdx.x * 256 + threadIdx.x;
  if (t >= NN * 16) return;
  int node = t >> 4, q = t & 15;
  float4 r = (node < NU) ? U4[(size_t)node * 16 + q] : V4[(size_t)(node - NU) * 16 + q];
  __half2 a = __floats2half2_rn(r.x, r.y);
  __half2 b = __floats2half2_rn(r.z, r.w);
  uint2 o;
  o.x = __builtin_bit_cast(unsigned int, a);
  o.y = __builtin_bit_cast(unsigned int, b);
  H0[(size_t)node * 16 + q] = o;
}

// ---------------- frontier marking ----------------
__global__ void k_mark_s(const int* __restrict__ snodes, const int* __restrict__ row_ptr,
                         const int2* __restrict__ pairs, int* __restrict__ need1,
                         int* __restrict__ need2) {
  int t = blockIdx.x * blockDim.x + threadIdx.x;
  if (t >= NS) return;
  int node = snodes[t];
  need2[node] = 1;
  need1[node] = 1;
  int s = row_ptr[node], e = row_ptr[node + 1];
  for (int j = s; j < e; ++j) need2[pairs[j].x] = 1;
}

__global__ void k_mark2(const int* __restrict__ row_ptr, const int2* __restrict__ pairs,
                        const int* __restrict__ need2, int* __restrict__ need1) {
  int n = blockIdx.x * blockDim.x + threadIdx.x;
  if (n >= NN || !need2[n]) return;
  int s = row_ptr[n], e = row_ptr[n + 1];
  for (int j = s; j < e; ++j) need1[pairs[j].x] = 1;
}

// ---------------- flag compaction: ballot + block scan, one atomic per block ----------------
__global__ void k_compact(const int* __restrict__ flags, int* __restrict__ list,
                          int* __restrict__ gcount) {
  __shared__ int wbase[4];
  int i = blockIdx.x * 256 + threadIdx.x;
  int f = (i < NN) ? flags[i] : 0;
  unsigned long long m = __ballot(f != 0);
  int lane = threadIdx.x & 63;
  int wv = threadIdx.x >> 6;
  int before = __popcll(m & ((1ull << lane) - 1ull));
  if (lane == 0) wbase[wv] = __popcll(m);
  __syncthreads();
  if (threadIdx.x == 0) {
    int c0 = wbase[0], c1 = wbase[1], c2 = wbase[2], c3 = wbase[3];
    int b0 = atomicAdd(gcount, c0 + c1 + c2 + c3);
    wbase[0] = b0;
    wbase[1] = b0 + c0;
    wbase[2] = b0 + c0 + c1;
    wbase[3] = b0 + c0 + c1 + c2;
  }
  __syncthreads();
  if (f) list[wbase[wv] + before] = i;
}

// ---------------- propagation: 16-lane group per listed node, fp16 in, fp32 acc ----------------
template <int BYPOS, int OUTF32>
__global__ void k_proph(const uint2* __restrict__ Hin, uint2* __restrict__ Hout,
                        float4* __restrict__ Fout, const int* __restrict__ row_ptr,
                        const int2* __restrict__ pairs, const int* __restrict__ list,
                        const int* __restrict__ countp, int cconst) {
  int n = cconst ? cconst : *countp;
  int lane = threadIdx.x & 63;
  int c = lane & 15;
  int sl = c & 7;
  int gstride = (gridDim.x * blockDim.x) >> 4;
  for (int gid = (blockIdx.x * blockDim.x + threadIdx.x) >> 4; gid < n; gid += gstride) {
    int node = list[gid];
    int start = row_ptr[node], end = row_ptr[node + 1];
    float4 acc = make_float4(0.f, 0.f, 0.f, 0.f);
    for (int t0 = start; t0 < end; t0 += 8) {
      int cap = end - t0;
      if (cap > 8) cap = 8;
      int2 mp = pairs[t0 + (sl < cap ? sl : 0)];  // coalesced tile-index load
      uint2 r[8];
      float vv[8];
#pragma unroll
      for (int k = 0; k < 8; ++k) {
        int srclane = (lane & 48) + k;
        int s = __shfl(mp.x, srclane);
        float v = __int_as_float(__shfl(mp.y, srclane));
        vv[k] = (k < cap) ? v : 0.f;
        r[k] = Hin[(size_t)s * 16 + c];  // 8 independent 8B gathers in flight
      }
#pragma unroll
      for (int k = 0; k < 8; ++k) {
        float2 f0 = __half22float2(__builtin_bit_cast(__half2, r[k].x));
        float2 f1 = __half22float2(__builtin_bit_cast(__half2, r[k].y));
        acc.x += vv[k] * f0.x;
        acc.y += vv[k] * f0.y;
        acc.z += vv[k] * f1.x;
        acc.w += vv[k] * f1.y;
      }
    }
    size_t op = BYPOS ? (size_t)gid : (size_t)node;
    if (OUTF32) {
      Fout[op * 16 + c] = acc;
    } else {
      __half2 a = __floats2half2_rn(acc.x, acc.y);
      __half2 b = __floats2half2_rn(acc.z, acc.w);
      uint2 o;
      o.x = __builtin_bit_cast(unsigned int, a);
      o.y = __builtin_bit_cast(unsigned int, b);
      Hout[op * 16 + c] = o;
    }
  }
}

// gather sampled nodes from fp32 U||V into Es[0]
__global__ void k_gather0(const float4* __restrict__ U4, const float4* __restrict__ V4,
                          float4* __restrict__ Es_l, const int* __restrict__ snodes) {
  int t = blockIdx.x * blockDim.x + threadIdx.x;
  if (t >= NS * 16) return;
  int p = t >> 4, q = t & 15;
  int node = snodes[p];
  Es_l[p * 16 + q] =
      (node < NU) ? U4[(size_t)node * 16 + q] : V4[(size_t)(node - NU) * 16 + q];
}

// gather sampled nodes from an fp16 table into Es[l] (fp32)
__global__ void k_gather_h(const uint2* __restrict__ Htab, float4* __restrict__ Es_l,
                           const int* __restrict__ snodes) {
  int t = blockIdx.x * blockDim.x + threadIdx.x;
  if (t >= NS * 16) return;
  int p = t >> 4, q = t & 15;
  int node = snodes[p];
  uint2 r = Htab[(size_t)node * 16 + q];
  float2 f0 = __half22float2(__builtin_bit_cast(__half2, r.x));
  float2 f1 = __half22float2(__builtin_bit_cast(__half2, r.y));
  Es_l[p * 16 + q] = make_float4(f0.x, f0.y, f1.x, f1.y);
}

// ---------------- attention precompute: Mt[h][b][j] = (Wk_h Wq_h^T)[j][b], P[h][d][j] ----------------
__global__ void k_prep(const float* __restrict__ Wq, const float* __restrict__ Wk,
                       const float* __restrict__ Wv, const float* __restrict__ Wo,
                       float* __restrict__ Mt, float* __restrict__ P) {
  int t = blockIdx.x * 256 + threadIdx.x;
  if (t >= 16384) return;
  if (t < 8192) {
    int h = t >> 12;
    int b = (t >> 6) & 63;
    int j = t & 63;
    float s = 0.f;
    for (int k = 0; k < 32; ++k) s += Wk[j * 64 + h * 32 + k] * Wq[b * 64 + h * 32 + k];
    Mt[h * 4096 + b * 64 + j] = s;
  } else {
    int t2 = t - 8192;
    int h = t2 >> 12;
    int d = (t2 >> 6) & 63;
    int j = t2 & 63;
    float s = 0.f;
    for (int v = 0; v < 32; ++v) s += Wv[d * 64 + h * 32 + v] * Wo[(h * 32 + v) * 64 + j];
    P[h * 4096 + d * 64 + j] = s;
  }
}

// ---------------- attention per node: wave per node, lane = dim ----------------
__global__ void k_attn2(const float* __restrict__ Es, const float* __restrict__ Mt,
                        const float* __restrict__ P, float* __restrict__ Eo) {
  __shared__ float sb[4][3 * 64];
  int wv = threadIdx.x >> 6, lane = threadIdx.x & 63;
  int p = blockIdx.x * 4 + wv;
  if (p >= NS) return;
  const float inv_scale = 0.17677669529663687f;  // 1/sqrt(32)

  float e0 = Es[(size_t)0 * NS * DD + p * DD + lane];
  float e1 = Es[(size_t)1 * NS * DD + p * DD + lane];
  float e2 = Es[(size_t)2 * NS * DD + p * DD + lane];
  float e3 = Es[(size_t)3 * NS * DD + p * DD + lane];
  sb[wv][lane] = e0;

  const float* M0 = Mt;
  const float* M1 = Mt + 4096;
  float g0 = 0.f, g1 = 0.f;
#pragma unroll 8
  for (int b = 0; b < 64; ++b) {
    float eb = sb[wv][b];
    g0 = fmaf(M0[b * 64 + lane], eb, g0);
    g1 = fmaf(M1[b * 64 + lane], eb, g1);
  }

  float el[4] = {e0, e1, e2, e3};
  float sc[4][2];
#pragma unroll
  for (int l = 0; l < 4; ++l) {
    float p0 = el[l] * g0, p1 = el[l] * g1;
#pragma unroll
    for (int o = 32; o; o >>= 1) {
      p0 += __shfl_xor(p0, o);
      p1 += __shfl_xor(p1, o);
    }
    sc[l][0] = p0 * inv_scale;
    sc[l][1] = p1 * inv_scale;
  }

  float ebar[2];
#pragma unroll
  for (int h = 0; h < 2; ++h) {
    float m = fmaxf(fmaxf(sc[0][h], sc[1][h]), fmaxf(sc[2][h], sc[3][h]));
    float x0 = expf(sc[0][h] - m), x1 = expf(sc[1][h] - m);
    float x2 = expf(sc[2][h] - m), x3 = expf(sc[3][h] - m);
    float inv = 1.f / (x0 + x1 + x2 + x3);
    ebar[h] = (x0 * e0 + x1 * e1 + x2 * e2 + x3 * e3) * inv;
  }
  sb[wv][64 + lane] = ebar[0];
  sb[wv][128 + lane] = ebar[1];

  const float* P0 = P;
  const float* P1 = P + 4096;
  float o = 0.f;
#pragma unroll 8
  for (int d = 0; d < 64; ++d) {
    float b0 = sb[wv][64 + d];
    float b1 = sb[wv][128 + d];
    o = fmaf(P0[d * 64 + lane], b0, o);
    o = fmaf(P1[d * 64 + lane], b1, o);
  }
  Eo[(size_t)p * DD + lane] = o;
}

// final pair scoring
__global__ void k_dot(const float* __restrict__ Eo, float* __restrict__ out) {
  int w = (blockIdx.x * blockDim.x + threadIdx.x) >> 6;
  int lane = threadIdx.x & 63;
  if (w >= BB) return;
  float pd = Eo[(size_t)w * DD + lane] * Eo[(size_t)(BB + w) * DD + lane];
#pragma unroll
  for (int o = 32; o; o >>= 1) pd += __shfl_xor(pd, o);
  if (lane == 0) out[w] = pd;
}

extern "C" void kernel_launch(void* const* d_in, const int* in_sizes, int n_in,
                              void* d_out, int out_size, void* d_ws, size_t ws_size,
                              hipStream_t stream) {
  const int* edge_src = (const int*)d_in[0];
  const int* edge_dst = (const int*)d_in[1];
  const float* edge_val = (const float*)d_in[2];
  const float* U_emb = (const float*)d_in[3];
  const float* V_emb = (const float*)d_in[4];
  const float* Wq = (const float*)d_in[5];
  const float* Wk = (const float*)d_in[6];
  const float* Wv = (const float*)d_in[7];
  const float* Wo = (const float*)d_in[8];
  const int* u = (const int*)d_in[9];
  const int* ii = (const int*)d_in[10];
  float* out = (float*)d_out;

  const float4* U4 = (const float4*)U_emb;
  const float4* V4 = (const float4*)V_emb;

  // workspace layout (16B-aligned base)
  float* Ea = (float*)d_ws;                          // 51.2MB region: H0 | H1 (fp16 tables)
  float* Eb = Ea + (size_t)NN * DD;                  // 51.2MB region: H2 (c_sv scratch before)
  float* Es = Eb + (size_t)NN * DD;                  // 4*NS*64 fp32
  float* Eo = Es + (size_t)4 * NS * DD;              // NS*64
  float* Mt = Eo + (size_t)NS * DD;                  // 2*4096
  float* Pm = Mt + 8192;                             // 2*4096
  int* row_ptr = (int*)(Pm + 8192);                  // NN+1 (padded to NN+4 for alignment)
  int* need1 = row_ptr + NN + 4;                     // NN (16B-aligned)
  int* need2 = need1 + NN;                           // NN (16B-aligned)
  int* bcur = need2 + NN;                            // NB2
  int* sbase = bcur + NB2;                           // NB2
  int* snodes = sbase + NB2;                         // NS
  int* cnt1 = snodes + NS;                           // 1
  int* cnt2 = cnt1 + 1;                              // 1
  uintptr_t pa = (uintptr_t)(cnt2 + 1);
  pa = (pa + 15) & ~(uintptr_t)15;
  int2* pairs = (int2*)pa;                           // NE int2

  uint2* H0 = (uint2*)Ea;                 // NN*16 uint2 = 25.6MB
  uint2* H1 = H0 + (size_t)NN * 16;       // 25.6MB
  uint2* H2 = (uint2*)Eb;                 // 25.6MB (written after c_sv dead)
  int2* c_sv = (int2*)Eb;                 // NB2*BCAP int2 = 12.8MB — dead after k_fine4
  // node lists live in the Es[3] quarter (Es[3] written by L3 prop, after lists are dead)
  int* n1list = (int*)(Es + (size_t)3 * NS * DD);    // <= NN ints
  int* n2list = n1list + NN;                         // <= NN ints

  float4* Es4 = (float4*)Es;

  // zero flags/counters with our own kernel (hipMemsetAsync's fill kernel costs ~39us each)
  k_zero<<<(2 * NN / 4 + 255) / 256, 256, 0, stream>>>((int4*)need1, cnt1);

  // attention weight precompute + sample list + fp16 E0 table (independent of CSR)
  k_prep<<<64, 256, 0, stream>>>(Wq, Wk, Wv, Wo, Mt, Pm);
  k_build_s<<<(NS + 255) / 256, 256, 0, stream>>>(u, ii, snodes);
  k_conv<<<(NN * 16 + 255) / 256, 256, 0, stream>>>(U4, V4, H0);

  // CSR build: init cursors -> coarse LDS-sort bin -> tiny scan -> fine place (+row_ptr)
  k_init2<<<1, 256, 0, stream>>>(bcur);
  k_coarse2<<<(NE + CH2 - 1) / CH2, 256, 0, stream>>>(edge_src, edge_dst, edge_val, bcur, c_sv);
  k_scan_seg<<<1, 256, 0, stream>>>(bcur, sbase, row_ptr);
  k_fine4<<<NB2, 256, 0, stream>>>(bcur, sbase, c_sv, pairs, row_ptr);

  // frontier marking + compaction
  k_mark_s<<<(NS + 255) / 256, 256, 0, stream>>>(snodes, row_ptr, pairs, need1, need2);
  k_mark2<<<(NN + 255) / 256, 256, 0, stream>>>(row_ptr, pairs, need2, need1);
  k_compact<<<(NN + 255) / 256, 256, 0, stream>>>(need1, n1list, cnt1);
  k_compact<<<(NN + 255) / 256, 256, 0, stream>>>(need2, n2list, cnt2);

  int ggrid = (NS * 16 + 255) / 256;

  k_gather0<<<ggrid, 256, 0, stream>>>(U4, V4, Es4 + (size_t)0 * NS * 16, snodes);
  // E1 = A @ E0 at need1 (fp16 in, fp16 out)
  k_proph<0, 0><<<2048, 256, 0, stream>>>(H0, H1, nullptr, row_ptr, pairs, n1list, cnt1, 0);
  k_gather_h<<<ggrid, 256, 0, stream>>>(H1, Es4 + (size_t)1 * NS * 16, snodes);
  // E2 = A @ E1 at need2
  k_proph<0, 0><<<2048, 256, 0, stream>>>(H1, H2, nullptr, row_ptr, pairs, n2list, cnt2, 0);
  k_gather_h<<<ggrid, 256, 0, stream>>>(H2, Es4 + (size_t)2 * NS * 16, snodes);
  // E3 at sampled nodes only, fp32 straight into Es[3]
  k_proph<1, 1><<<512, 256, 0, stream>>>(H2, nullptr, Es4 + (size_t)3 * NS * 16, row_ptr, pairs,
                                         snodes, nullptr, NS);

  k_attn2<<<(NS + 3) / 4, 256, 0, stream>>>(Es, Mt, Pm, Eo);
  k_dot<<<(BB * 64 + 255) / 256, 256, 0, stream>>>(Eo, out);
}

// Round 10
// 132.760 us; speedup vs baseline: 1.7233x; 1.3647x over previous
//
#include <hip/hip_runtime.h>
#include <hip/hip_fp16.h>

#define NU 120000
#define NI 80000
#define NN 200000
#define DD 64
#define NE 1280000
#define BB 4096
#define NS 8192    // 2*B sampled nodes
#define NB2 196    // ceil(NN/1024) buckets, bucket = dst>>10
#define BCAP 8192  // slack capacity per bucket segment (mean 6530, +20 sigma)
#define CH2 4096   // coarse chunk

// setup mega-kernel block partition
#define CB 313         // coarse2 blocks = ceil(NE/CH2)
#define CONVB 3125     // conv blocks = NN*16/(256*4)
#define PREPB 64
#define BSB 32
// prop1 mega-kernel partition
#define P1B 2048
#define G0B 512        // NS*16/256
#define NLB 32         // NS/256

// ---------------- pre: zero cursors/counters ----------------
__global__ void k_pre(int* __restrict__ bcur, int* __restrict__ n2cnt) {
  int t = threadIdx.x;
  if (t < NB2) bcur[t] = 0;
  if (t == 0) *n2cnt = 0;
}

// ---------------- device bodies ----------------
__device__ __forceinline__ void d_coarse2(int rel, const int* __restrict__ src,
                                          const int* __restrict__ dst,
                                          const float* __restrict__ val, int* __restrict__ bcur,
                                          int2* __restrict__ c_sv, int2* sv, unsigned char* map8,
                                          int* hist, int* lbase, int* gbase, int* s) {
  int t = threadIdx.x;
  hist[t] = 0;
  __syncthreads();
  int e0 = rel * CH2;
  int d_[16];
#pragma unroll
  for (int k = 0; k < 16; ++k) {
    int e = e0 + k * 256 + t;
    d_[k] = (e < NE) ? dst[e] : -1;
    if (d_[k] >= 0) atomicAdd(&hist[d_[k] >> 10], 1);
  }
  __syncthreads();
  int x = hist[t];
  s[t] = x;
  __syncthreads();
  for (int off = 1; off < 256; off <<= 1) {
    int v = (t >= off) ? s[t - off] : 0;
    __syncthreads();
    s[t] += v;
    __syncthreads();
  }
  int lb = s[t] - x;
  lbase[t] = lb;
  gbase[t] = (x && t < NB2) ? (t * BCAP + atomicAdd(&bcur[t], x)) : 0;
  for (int k = lb; k < lb + x; ++k) map8[k] = (unsigned char)t;
  hist[t] = 0;  // reuse as in-block cursor
  __syncthreads();
#pragma unroll
  for (int k = 0; k < 16; ++k) {
    int e = e0 + k * 256 + t;
    if (d_[k] >= 0) {
      int b = d_[k] >> 10;
      int lp = lbase[b] + atomicAdd(&hist[b], 1);
      sv[lp] = make_int2(src[e] | ((d_[k] & 1023) << 18), __float_as_int(val[e]));
    }
  }
  __syncthreads();
  int nval = NE - e0;
  if (nval > CH2) nval = CH2;
  for (int sidx = t; sidx < nval; sidx += 256) {
    int b = map8[sidx];
    c_sv[(size_t)gbase[b] + sidx - lbase[b]] = sv[sidx];  // coalesced runs
  }
}

__device__ __forceinline__ void d_conv(int rel, const float4* __restrict__ U4,
                                       const float4* __restrict__ V4, uint2* __restrict__ H0) {
  int t = threadIdx.x;
  float4 r[4];
#pragma unroll
  for (int k = 0; k < 4; ++k) {
    int idx = rel * 1024 + k * 256 + t;
    int node = idx >> 4, q = idx & 15;
    r[k] = (node < NU) ? U4[(size_t)node * 16 + q] : V4[(size_t)(node - NU) * 16 + q];
  }
#pragma unroll
  for (int k = 0; k < 4; ++k) {
    int idx = rel * 1024 + k * 256 + t;
    __half2 a = __floats2half2_rn(r[k].x, r[k].y);
    __half2 b = __floats2half2_rn(r[k].z, r[k].w);
    uint2 o;
    o.x = __builtin_bit_cast(unsigned int, a);
    o.y = __builtin_bit_cast(unsigned int, b);
    H0[idx] = o;
  }
}

__device__ __forceinline__ void d_prep(int rel, const float* __restrict__ Wq,
                                       const float* __restrict__ Wk, const float* __restrict__ Wv,
                                       const float* __restrict__ Wo, float* __restrict__ Mt,
                                       float* __restrict__ P) {
  int t = rel * 256 + threadIdx.x;
  if (t < 8192) {
    int h = t >> 12;
    int b = (t >> 6) & 63;
    int j = t & 63;
    float s = 0.f;
    for (int k = 0; k < 32; ++k) s += Wk[j * 64 + h * 32 + k] * Wq[b * 64 + h * 32 + k];
    Mt[h * 4096 + b * 64 + j] = s;
  } else if (t < 16384) {
    int t2 = t - 8192;
    int h = t2 >> 12;
    int d = (t2 >> 6) & 63;
    int j = t2 & 63;
    float s = 0.f;
    for (int v = 0; v < 32; ++v) s += Wv[d * 64 + h * 32 + v] * Wo[(h * 32 + v) * 64 + j];
    P[h * 4096 + d * 64 + j] = s;
  }
}

// ---------------- SETUP mega-kernel: coarse2 | conv | prep | build_s ----------------
__global__ void k_setup(const int* __restrict__ src, const int* __restrict__ dst,
                        const float* __restrict__ val, int* __restrict__ bcur,
                        int2* __restrict__ c_sv, const float4* __restrict__ U4,
                        const float4* __restrict__ V4, uint2* __restrict__ H0,
                        const float* __restrict__ Wq, const float* __restrict__ Wk,
                        const float* __restrict__ Wv, const float* __restrict__ Wo,
                        float* __restrict__ Mt, float* __restrict__ P,
                        const int* __restrict__ u, const int* __restrict__ ii,
                        int* __restrict__ snodes) {
  __shared__ int2 sv[CH2];
  __shared__ unsigned char map8[CH2];
  __shared__ int hist[256], lbase[256], gbase[256], s[256];
  int b = blockIdx.x;
  if (b < CB) {
    d_coarse2(b, src, dst, val, bcur, c_sv, sv, map8, hist, lbase, gbase, s);
  } else if (b < CB + CONVB) {
    d_conv(b - CB, U4, V4, H0);
  } else if (b < CB + CONVB + PREPB) {
    d_prep(b - CB - CONVB, Wq, Wk, Wv, Wo, Mt, P);
  } else {
    int t = (b - CB - CONVB - PREPB) * 256 + threadIdx.x;
    if (t < NS) snodes[t] = (t < BB) ? u[t] : NU + ii[t - BB];
  }
}

// ---------------- fine: one block per bucket; inline bucket-scan; row_ptr + pairs ----------------
__global__ void k_fine4b(const int* __restrict__ bcur, const int2* __restrict__ c_sv,
                         int2* __restrict__ pairs, int* __restrict__ row_ptr) {
  __shared__ int cnt[1024];
  __shared__ int pre[1024];
  __shared__ int cur[1024];
  __shared__ int s[256];
  __shared__ int bs[256];
  int b = blockIdx.x, t = threadIdx.x;
  // inline exclusive scan of the 196 bucket counts -> out0
  int bc = (t < NB2) ? bcur[t] : 0;
  bs[t] = bc;
  __syncthreads();
  for (int off = 1; off < 256; off <<= 1) {
    int v = (t >= off) ? bs[t - off] : 0;
    __syncthreads();
    bs[t] += v;
    __syncthreads();
  }
  int segN = bcur[b];
  int out0 = bs[b] - segN;
  int seg0 = b * BCAP;
  for (int k = t; k < 1024; k += 256) cnt[k] = 0;
  __syncthreads();
  for (int e = t; e < segN; e += 256) atomicAdd(&cnt[(c_sv[seg0 + e].x >> 18) & 1023], 1);
  __syncthreads();
  int a0 = cnt[4 * t], a1 = cnt[4 * t + 1], a2 = cnt[4 * t + 2], a3 = cnt[4 * t + 3];
  int tot = a0 + a1 + a2 + a3;
  s[t] = tot;
  __syncthreads();
  for (int off = 1; off < 256; off <<= 1) {
    int v = (t >= off) ? s[t - off] : 0;
    __syncthreads();
    s[t] += v;
    __syncthreads();
  }
  int base = s[t] - tot;
  pre[4 * t] = base;
  pre[4 * t + 1] = base + a0;
  pre[4 * t + 2] = base + a0 + a1;
  pre[4 * t + 3] = base + a0 + a1 + a2;
  int node0 = b << 10;
#pragma unroll
  for (int k = 0; k < 4; ++k) {
    int n = node0 + 4 * t + k;
    if (n < NN) row_ptr[n] = out0 + pre[4 * t + k];
  }
  if (b == 0 && t == 0) row_ptr[NN] = NE;
  for (int k = t; k < 1024; k += 256) cur[k] = 0;
  __syncthreads();
  for (int e = t; e < segN; e += 256) {
    int2 svv = c_sv[seg0 + e];
    int ld = (svv.x >> 18) & 1023;
    int off = atomicAdd(&cur[ld], 1);
    pairs[out0 + pre[ld] + off] = make_int2(svv.x & 0x3FFFF, svv.y);
  }
}

// ---------------- propagation device body: 16-lane group per node ----------------
template <int ULIST, int BYPOS, int OUTF32>
__device__ __forceinline__ void d_prop(const uint2* __restrict__ Hin, uint2* __restrict__ Hout,
                                       float4* __restrict__ Fout,
                                       const int* __restrict__ row_ptr,
                                       const int2* __restrict__ pairs,
                                       const int* __restrict__ list,
                                       const int* __restrict__ countp, int cconst, int relbid,
                                       int nblk) {
  int n = countp ? *countp : cconst;
  int lane = threadIdx.x & 63;
  int c = lane & 15;
  int sl = c & 7;
  int gstride = (nblk * 256) >> 4;
  for (int gid = (relbid * 256 + (int)threadIdx.x) >> 4; gid < n; gid += gstride) {
    int node = ULIST ? list[gid] : gid;
    int start = row_ptr[node], end = row_ptr[node + 1];
    float4 acc = make_float4(0.f, 0.f, 0.f, 0.f);
    for (int t0 = start; t0 < end; t0 += 8) {
      int cap = end - t0;
      if (cap > 8) cap = 8;
      int2 mp = pairs[t0 + (sl < cap ? sl : 0)];  // coalesced tile-index load
      uint2 r[8];
      float vv[8];
#pragma unroll
      for (int k = 0; k < 8; ++k) {
        int srclane = (lane & 48) + k;
        int sidx = __shfl(mp.x, srclane);
        float v = __int_as_float(__shfl(mp.y, srclane));
        vv[k] = (k < cap) ? v : 0.f;
        r[k] = Hin[(size_t)sidx * 16 + c];  // 8 independent 8B gathers in flight
      }
#pragma unroll
      for (int k = 0; k < 8; ++k) {
        float2 f0 = __half22float2(__builtin_bit_cast(__half2, r[k].x));
        float2 f1 = __half22float2(__builtin_bit_cast(__half2, r[k].y));
        acc.x += vv[k] * f0.x;
        acc.y += vv[k] * f0.y;
        acc.z += vv[k] * f1.x;
        acc.w += vv[k] * f1.y;
      }
    }
    size_t op = BYPOS ? (size_t)gid : (size_t)node;
    if (OUTF32) {
      Fout[op * 16 + c] = acc;
    } else {
      __half2 a = __floats2half2_rn(acc.x, acc.y);
      __half2 bq = __floats2half2_rn(acc.z, acc.w);
      uint2 o;
      o.x = __builtin_bit_cast(unsigned int, a);
      o.y = __builtin_bit_cast(unsigned int, bq);
      Hout[op * 16 + c] = o;
    }
  }
}

__device__ __forceinline__ void d_gather_h(int rel, const uint2* __restrict__ Htab,
                                           float4* __restrict__ Es_l,
                                           const int* __restrict__ snodes) {
  int t = rel * 256 + threadIdx.x;
  if (t >= NS * 16) return;
  int p = t >> 4, q = t & 15;
  int node = snodes[p];
  uint2 r = Htab[(size_t)node * 16 + q];
  float2 f0 = __half22float2(__builtin_bit_cast(__half2, r.x));
  float2 f1 = __half22float2(__builtin_bit_cast(__half2, r.y));
  Es_l[p * 16 + q] = make_float4(f0.x, f0.y, f1.x, f1.y);
}

// ---------------- PROP1 mega-kernel: prop1-all | gather0 | nbrlist ----------------
__global__ void k_prop1m(const uint2* __restrict__ H0, uint2* __restrict__ H1,
                         const float4* __restrict__ U4, const float4* __restrict__ V4,
                         float4* __restrict__ Es0, const int* __restrict__ snodes,
                         const int* __restrict__ row_ptr, const int2* __restrict__ pairs,
                         int* __restrict__ n2list, int* __restrict__ n2cnt) {
  int b = blockIdx.x;
  if (b < P1B) {
    d_prop<0, 0, 0>(H0, H1, nullptr, row_ptr, pairs, nullptr, nullptr, NN, b, P1B);
  } else if (b < P1B + G0B) {
    int t = (b - P1B) * 256 + threadIdx.x;
    if (t < NS * 16) {
      int p = t >> 4, q = t & 15;
      int node = snodes[p];
      Es0[p * 16 + q] =
          (node < NU) ? U4[(size_t)node * 16 + q] : V4[(size_t)(node - NU) * 16 + q];
    }
  } else {
    int idx = (b - P1B - G0B) * 256 + threadIdx.x;
    if (idx < NS) {
      int node = snodes[idx];
      int s0 = row_ptr[node], e0 = row_ptr[node + 1];
      int pos = atomicAdd(n2cnt, e0 - s0 + 1);
      n2list[pos++] = node;
      for (int j = s0; j < e0; ++j) n2list[pos++] = pairs[j].x;
    }
  }
}

// ---------------- STAGE2: gather_h(H1->Es1) | prop2 (n2list, dupes benign) ----------------
__global__ void k_stage2(const uint2* __restrict__ H1, uint2* __restrict__ H2,
                         float4* __restrict__ Es1, const int* __restrict__ snodes,
                         const int* __restrict__ row_ptr, const int2* __restrict__ pairs,
                         const int* __restrict__ n2list, const int* __restrict__ n2cnt) {
  int b = blockIdx.x;
  if (b < 512) {
    d_gather_h(b, H1, Es1, snodes);
  } else {
    d_prop<1, 0, 0>(H1, H2, nullptr, row_ptr, pairs, n2list, n2cnt, 0, b - 512, 1024);
  }
}

// ---------------- STAGE3: gather_h(H2->Es2) | prop3 (samples -> Es3 fp32) ----------------
__global__ void k_stage3(const uint2* __restrict__ H2, float4* __restrict__ Es2,
                         float4* __restrict__ Es3, const int* __restrict__ snodes,
                         const int* __restrict__ row_ptr, const int2* __restrict__ pairs) {
  int b = blockIdx.x;
  if (b < 512) {
    d_gather_h(b, H2, Es2, snodes);
  } else {
    d_prop<1, 1, 1>(H2, nullptr, Es3, row_ptr, pairs, snodes, nullptr, NS, b - 512, 512);
  }
}

// ---------------- fused attention + pair scoring: one wave per pair ----------------
__global__ void k_attn3(const float* __restrict__ Es, const float* __restrict__ Mt,
                        const float* __restrict__ P, float* __restrict__ out) {
  __shared__ float sb[4][3 * 64];
  int wv = threadIdx.x >> 6, lane = threadIdx.x & 63;
  int w = blockIdx.x * 4 + wv;
  if (w >= BB) return;
  const float inv_scale = 0.17677669529663687f;  // 1/sqrt(32)
  const float* M0 = Mt;
  const float* M1 = Mt + 4096;
  const float* P0 = P;
  const float* P1 = P + 4096;
  float eo[2];
#pragma unroll
  for (int side = 0; side < 2; ++side) {
    int p = side ? (BB + w) : w;
    float e0 = Es[(size_t)0 * NS * DD + p * DD + lane];
    float e1 = Es[(size_t)1 * NS * DD + p * DD + lane];
    float e2 = Es[(size_t)2 * NS * DD + p * DD + lane];
    float e3 = Es[(size_t)3 * NS * DD + p * DD + lane];
    sb[wv][lane] = e0;

    float g0 = 0.f, g1 = 0.f;
#pragma unroll 8
    for (int b = 0; b < 64; ++b) {
      float eb = sb[wv][b];  // LDS same-address broadcast (wave-synchronous)
      g0 = fmaf(M0[b * 64 + lane], eb, g0);
      g1 = fmaf(M1[b * 64 + lane], eb, g1);
    }

    float el[4] = {e0, e1, e2, e3};
    float sc[4][2];
#pragma unroll
    for (int l = 0; l < 4; ++l) {
      float p0 = el[l] * g0, p1 = el[l] * g1;
#pragma unroll
      for (int o = 32; o; o >>= 1) {
        p0 += __shfl_xor(p0, o);
        p1 += __shfl_xor(p1, o);
      }
      sc[l][0] = p0 * inv_scale;
      sc[l][1] = p1 * inv_scale;
    }

    float ebar[2];
#pragma unroll
    for (int h = 0; h < 2; ++h) {
      float m = fmaxf(fmaxf(sc[0][h], sc[1][h]), fmaxf(sc[2][h], sc[3][h]));
      float x0 = expf(sc[0][h] - m), x1 = expf(sc[1][h] - m);
      float x2 = expf(sc[2][h] - m), x3 = expf(sc[3][h] - m);
      float inv = 1.f / (x0 + x1 + x2 + x3);
      ebar[h] = (x0 * e0 + x1 * e1 + x2 * e2 + x3 * e3) * inv;
    }
    sb[wv][64 + lane] = ebar[0];
    sb[wv][128 + lane] = ebar[1];

    float o = 0.f;
#pragma unroll 8
    for (int d = 0; d < 64; ++d) {
      float b0 = sb[wv][64 + d];
      float b1 = sb[wv][128 + d];
      o = fmaf(P0[d * 64 + lane], b0, o);
      o = fmaf(P1[d * 64 + lane], b1, o);
    }
    eo[side] = o;
  }
  float pd = eo[0] * eo[1];
#pragma unroll
  for (int o = 32; o; o >>= 1) pd += __shfl_xor(pd, o);
  if (lane == 0) out[w] = pd;
}

extern "C" void kernel_launch(void* const* d_in, const int* in_sizes, int n_in,
                              void* d_out, int out_size, void* d_ws, size_t ws_size,
                              hipStream_t stream) {
  const int* edge_src = (const int*)d_in[0];
  const int* edge_dst = (const int*)d_in[1];
  const float* edge_val = (const float*)d_in[2];
  const float* U_emb = (const float*)d_in[3];
  const float* V_emb = (const float*)d_in[4];
  const float* Wq = (const float*)d_in[5];
  const float* Wk = (const float*)d_in[6];
  const float* Wv = (const float*)d_in[7];
  const float* Wo = (const float*)d_in[8];
  const int* u = (const int*)d_in[9];
  const int* ii = (const int*)d_in[10];
  float* out = (float*)d_out;

  const float4* U4 = (const float4*)U_emb;
  const float4* V4 = (const float4*)V_emb;

  // workspace layout (16B-aligned base)
  float* Ea = (float*)d_ws;                          // H0 | H1 (fp16 tables, 25.6MB each)
  float* Eb = Ea + (size_t)NN * DD;                  // H2 (aliases c_sv scratch before)
  float* Es = Eb + (size_t)NN * DD;                  // 4*NS*64 fp32
  float* Mt = Es + (size_t)4 * NS * DD;              // 2*4096
  float* Pm = Mt + 8192;                             // 2*4096
  int* row_ptr = (int*)(Pm + 8192);                  // NN+1 (+pad)
  int* bcur = row_ptr + NN + 4;                      // NB2
  int* snodes = bcur + NB2;                          // NS
  int* n2cnt = snodes + NS;                          // 1
  uintptr_t pa = (uintptr_t)(n2cnt + 1);
  pa = (pa + 15) & ~(uintptr_t)15;
  int2* pairs = (int2*)pa;                           // NE int2

  uint2* H0 = (uint2*)Ea;                 // NN*16 uint2
  uint2* H1 = H0 + (size_t)NN * 16;
  uint2* H2 = (uint2*)Eb;                 // written after c_sv dead
  int2* c_sv = (int2*)Eb;                 // NB2*BCAP int2 = 12.8MB — dead after k_fine4b
  int* n2list = (int*)(Es + (size_t)3 * NS * DD);  // in Es[3] quarter; dead before stage3 writes

  float4* Es4 = (float4*)Es;

  k_pre<<<1, 256, 0, stream>>>(bcur, n2cnt);
  k_setup<<<CB + CONVB + PREPB + BSB, 256, 0, stream>>>(edge_src, edge_dst, edge_val, bcur, c_sv,
                                                        U4, V4, H0, Wq, Wk, Wv, Wo, Mt, Pm, u, ii,
                                                        snodes);
  k_fine4b<<<NB2, 256, 0, stream>>>(bcur, c_sv, pairs, row_ptr);
  k_prop1m<<<P1B + G0B + NLB, 256, 0, stream>>>(H0, H1, U4, V4, Es4 + (size_t)0 * NS * 16, snodes,
                                                row_ptr, pairs, n2list, n2cnt);
  k_stage2<<<512 + 1024, 256, 0, stream>>>(H1, H2, Es4 + (size_t)1 * NS * 16, snodes, row_ptr,
                                           pairs, n2list, n2cnt);
  k_stage3<<<512 + 512, 256, 0, stream>>>(H2, Es4 + (size_t)2 * NS * 16,
                                          Es4 + (size_t)3 * NS * 16, snodes, row_ptr, pairs);
  k_attn3<<<(BB + 3) / 4, 256, 0, stream>>>(Es, Mt, Pm, out);
}

// Round 11
// 132.751 us; speedup vs baseline: 1.7234x; 1.0001x over previous
//
#include <hip/hip_runtime.h>
#include <hip/hip_fp16.h>

#define NU 120000
#define NI 80000
#define NN 200000
#define DD 64
#define NE 1280000
#define BB 4096
#define NS 8192    // 2*B sampled nodes
#define NB2 196    // ceil(NN/1024) buckets, bucket = dst>>10
#define BCAP 8192  // slack capacity per bucket segment (mean 6530, +20 sigma)
#define CH2 4096   // coarse chunk

// fine4m mega-kernel block partition
#define FB 196
#define CONVB 3125     // conv blocks = NN*16/(256*4)
#define PREPB 64
#define BSB 32
// prop1 mega-kernel partition
#define P1B 2048
#define G0B 512        // NS*16/256
#define NLB 32         // NS/256

// ---------------- pre: zero cursors/counters ----------------
__global__ void k_pre(int* __restrict__ bcur, int* __restrict__ n2cnt) {
  int t = threadIdx.x;
  if (t < NB2) bcur[t] = 0;
  if (t == 0) *n2cnt = 0;
}

// ---------------- coarse: LDS counting-sort of 4096 edges into 196 buckets ----------------
__global__ void k_coarse2(const int* __restrict__ src, const int* __restrict__ dst,
                          const float* __restrict__ val, int* __restrict__ bcur,
                          int2* __restrict__ c_sv) {
  __shared__ int2 sv[CH2];             // 32KB sorted staging
  __shared__ unsigned char map8[CH2];  // slot -> bucket
  __shared__ int hist[256];
  __shared__ int lbase[256];
  __shared__ int gbase[256];
  __shared__ int s[256];
  int t = threadIdx.x;
  hist[t] = 0;
  __syncthreads();
  int e0 = blockIdx.x * CH2;
  int d_[16];
#pragma unroll
  for (int k = 0; k < 16; ++k) {
    int e = e0 + k * 256 + t;
    d_[k] = (e < NE) ? dst[e] : -1;
    if (d_[k] >= 0) atomicAdd(&hist[d_[k] >> 10], 1);
  }
  __syncthreads();
  int x = hist[t];
  s[t] = x;
  __syncthreads();
  for (int off = 1; off < 256; off <<= 1) {
    int v = (t >= off) ? s[t - off] : 0;
    __syncthreads();
    s[t] += v;
    __syncthreads();
  }
  int lb = s[t] - x;
  lbase[t] = lb;
  gbase[t] = (x && t < NB2) ? (t * BCAP + atomicAdd(&bcur[t], x)) : 0;
  for (int k = lb; k < lb + x; ++k) map8[k] = (unsigned char)t;
  hist[t] = 0;  // reuse as in-block cursor
  __syncthreads();
#pragma unroll
  for (int k = 0; k < 16; ++k) {
    int e = e0 + k * 256 + t;
    if (d_[k] >= 0) {
      int b = d_[k] >> 10;
      int lp = lbase[b] + atomicAdd(&hist[b], 1);
      sv[lp] = make_int2(src[e] | ((d_[k] & 1023) << 18), __float_as_int(val[e]));
    }
  }
  __syncthreads();
  int nval = NE - e0;
  if (nval > CH2) nval = CH2;
  for (int sidx = t; sidx < nval; sidx += 256) {
    int b = map8[sidx];
    c_sv[(size_t)gbase[b] + sidx - lbase[b]] = sv[sidx];  // coalesced runs
  }
}

// ---------------- device bodies for fine4m ----------------
__device__ __forceinline__ void d_conv(int rel, const float4* __restrict__ U4,
                                       const float4* __restrict__ V4, uint2* __restrict__ H0) {
  int t = threadIdx.x;
  float4 r[4];
#pragma unroll
  for (int k = 0; k < 4; ++k) {
    int idx = rel * 1024 + k * 256 + t;
    int node = idx >> 4, q = idx & 15;
    r[k] = (node < NU) ? U4[(size_t)node * 16 + q] : V4[(size_t)(node - NU) * 16 + q];
  }
#pragma unroll
  for (int k = 0; k < 4; ++k) {
    int idx = rel * 1024 + k * 256 + t;
    __half2 a = __floats2half2_rn(r[k].x, r[k].y);
    __half2 b = __floats2half2_rn(r[k].z, r[k].w);
    uint2 o;
    o.x = __builtin_bit_cast(unsigned int, a);
    o.y = __builtin_bit_cast(unsigned int, b);
    H0[idx] = o;
  }
}

__device__ __forceinline__ void d_prep(int rel, const float* __restrict__ Wq,
                                       const float* __restrict__ Wk, const float* __restrict__ Wv,
                                       const float* __restrict__ Wo, float* __restrict__ Mt,
                                       float* __restrict__ P) {
  int t = rel * 256 + threadIdx.x;
  if (t < 8192) {
    int h = t >> 12;
    int b = (t >> 6) & 63;
    int j = t & 63;
    float s = 0.f;
    for (int k = 0; k < 32; ++k) s += Wk[j * 64 + h * 32 + k] * Wq[b * 64 + h * 32 + k];
    Mt[h * 4096 + b * 64 + j] = s;
  } else if (t < 16384) {
    int t2 = t - 8192;
    int h = t2 >> 12;
    int d = (t2 >> 6) & 63;
    int j = t2 & 63;
    float s = 0.f;
    for (int v = 0; v < 32; ++v) s += Wv[d * 64 + h * 32 + v] * Wo[(h * 32 + v) * 64 + j];
    P[h * 4096 + d * 64 + j] = s;
  }
}

// ---------------- FINE4M mega-kernel: fine4b | conv | prep | build_s (14KB LDS) ----------------
__global__ void k_fine4m(const int* __restrict__ bcur, const int2* __restrict__ c_sv,
                         int2* __restrict__ pairs, int* __restrict__ row_ptr,
                         const float4* __restrict__ U4, const float4* __restrict__ V4,
                         uint2* __restrict__ H0, const float* __restrict__ Wq,
                         const float* __restrict__ Wk, const float* __restrict__ Wv,
                         const float* __restrict__ Wo, float* __restrict__ Mt,
                         float* __restrict__ P, const int* __restrict__ u,
                         const int* __restrict__ ii, int* __restrict__ snodes) {
  __shared__ int cnt[1024];
  __shared__ int pre[1024];
  __shared__ int cur[1024];
  __shared__ int s[256];
  __shared__ int bs[256];
  int b = blockIdx.x, t = threadIdx.x;
  if (b >= FB) {
    int r = b - FB;
    if (r < CONVB) {
      d_conv(r, U4, V4, H0);
    } else if (r < CONVB + PREPB) {
      d_prep(r - CONVB, Wq, Wk, Wv, Wo, Mt, P);
    } else {
      int tt = (r - CONVB - PREPB) * 256 + t;
      if (tt < NS) snodes[tt] = (tt < BB) ? u[tt] : NU + ii[tt - BB];
    }
    return;
  }
  // ---- fine4b body: one block per bucket ----
  int bc = (t < NB2) ? bcur[t] : 0;
  bs[t] = bc;
  __syncthreads();
  for (int off = 1; off < 256; off <<= 1) {
    int v = (t >= off) ? bs[t - off] : 0;
    __syncthreads();
    bs[t] += v;
    __syncthreads();
  }
  int segN = bcur[b];
  int out0 = bs[b] - segN;
  int seg0 = b * BCAP;
  for (int k = t; k < 1024; k += 256) cnt[k] = 0;
  __syncthreads();
  for (int e = t; e < segN; e += 256) atomicAdd(&cnt[(c_sv[seg0 + e].x >> 18) & 1023], 1);
  __syncthreads();
  int a0 = cnt[4 * t], a1 = cnt[4 * t + 1], a2 = cnt[4 * t + 2], a3 = cnt[4 * t + 3];
  int tot = a0 + a1 + a2 + a3;
  s[t] = tot;
  __syncthreads();
  for (int off = 1; off < 256; off <<= 1) {
    int v = (t >= off) ? s[t - off] : 0;
    __syncthreads();
    s[t] += v;
    __syncthreads();
  }
  int base = s[t] - tot;
  pre[4 * t] = base;
  pre[4 * t + 1] = base + a0;
  pre[4 * t + 2] = base + a0 + a1;
  pre[4 * t + 3] = base + a0 + a1 + a2;
  int node0 = b << 10;
#pragma unroll
  for (int k = 0; k < 4; ++k) {
    int n = node0 + 4 * t + k;
    if (n < NN) row_ptr[n] = out0 + pre[4 * t + k];
  }
  if (b == 0 && t == 0) row_ptr[NN] = NE;
  for (int k = t; k < 1024; k += 256) cur[k] = 0;
  __syncthreads();
  for (int e = t; e < segN; e += 256) {
    int2 svv = c_sv[seg0 + e];
    int ld = (svv.x >> 18) & 1023;
    int off = atomicAdd(&cur[ld], 1);
    pairs[out0 + pre[ld] + off] = make_int2(svv.x & 0x3FFFF, svv.y);
  }
}

// ---------------- propagation device body: 16-lane group per node ----------------
template <int ULIST, int BYPOS, int OUTF32>
__device__ __forceinline__ void d_prop(const uint2* __restrict__ Hin, uint2* __restrict__ Hout,
                                       float4* __restrict__ Fout,
                                       const int* __restrict__ row_ptr,
                                       const int2* __restrict__ pairs,
                                       const int* __restrict__ list,
                                       const int* __restrict__ countp, int cconst, int relbid,
                                       int nblk) {
  int n = countp ? *countp : cconst;
  int lane = threadIdx.x & 63;
  int c = lane & 15;
  int sl = c & 7;
  int gstride = (nblk * 256) >> 4;
  for (int gid = (relbid * 256 + (int)threadIdx.x) >> 4; gid < n; gid += gstride) {
    int node = ULIST ? list[gid] : gid;
    int start = row_ptr[node], end = row_ptr[node + 1];
    float4 acc = make_float4(0.f, 0.f, 0.f, 0.f);
    for (int t0 = start; t0 < end; t0 += 8) {
      int cap = end - t0;
      if (cap > 8) cap = 8;
      int2 mp = pairs[t0 + (sl < cap ? sl : 0)];  // coalesced tile-index load
      uint2 r[8];
      float vv[8];
#pragma unroll
      for (int k = 0; k < 8; ++k) {
        int srclane = (lane & 48) + k;
        int sidx = __shfl(mp.x, srclane);
        float v = __int_as_float(__shfl(mp.y, srclane));
        vv[k] = (k < cap) ? v : 0.f;
        r[k] = Hin[(size_t)sidx * 16 + c];  // 8 independent 8B gathers in flight
      }
#pragma unroll
      for (int k = 0; k < 8; ++k) {
        float2 f0 = __half22float2(__builtin_bit_cast(__half2, r[k].x));
        float2 f1 = __half22float2(__builtin_bit_cast(__half2, r[k].y));
        acc.x += vv[k] * f0.x;
        acc.y += vv[k] * f0.y;
        acc.z += vv[k] * f1.x;
        acc.w += vv[k] * f1.y;
      }
    }
    size_t op = BYPOS ? (size_t)gid : (size_t)node;
    if (OUTF32) {
      Fout[op * 16 + c] = acc;
    } else {
      __half2 a = __floats2half2_rn(acc.x, acc.y);
      __half2 bq = __floats2half2_rn(acc.z, acc.w);
      uint2 o;
      o.x = __builtin_bit_cast(unsigned int, a);
      o.y = __builtin_bit_cast(unsigned int, bq);
      Hout[op * 16 + c] = o;
    }
  }
}

__device__ __forceinline__ void d_gather_h(int rel, const uint2* __restrict__ Htab,
                                           float4* __restrict__ Es_l,
                                           const int* __restrict__ snodes) {
  int t = rel * 256 + threadIdx.x;
  if (t >= NS * 16) return;
  int p = t >> 4, q = t & 15;
  int node = snodes[p];
  uint2 r = Htab[(size_t)node * 16 + q];
  float2 f0 = __half22float2(__builtin_bit_cast(__half2, r.x));
  float2 f1 = __half22float2(__builtin_bit_cast(__half2, r.y));
  Es_l[p * 16 + q] = make_float4(f0.x, f0.y, f1.x, f1.y);
}

// ---------------- PROP1 mega-kernel: prop1-all | gather0 | nbrlist ----------------
__global__ void k_prop1m(const uint2* __restrict__ H0, uint2* __restrict__ H1,
                         const float4* __restrict__ U4, const float4* __restrict__ V4,
                         float4* __restrict__ Es0, const int* __restrict__ snodes,
                         const int* __restrict__ row_ptr, const int2* __restrict__ pairs,
                         int* __restrict__ n2list, int* __restrict__ n2cnt) {
  int b = blockIdx.x;
  if (b < P1B) {
    d_prop<0, 0, 0>(H0, H1, nullptr, row_ptr, pairs, nullptr, nullptr, NN, b, P1B);
  } else if (b < P1B + G0B) {
    int t = (b - P1B) * 256 + threadIdx.x;
    if (t < NS * 16) {
      int p = t >> 4, q = t & 15;
      int node = snodes[p];
      Es0[p * 16 + q] =
          (node < NU) ? U4[(size_t)node * 16 + q] : V4[(size_t)(node - NU) * 16 + q];
    }
  } else {
    int idx = (b - P1B - G0B) * 256 + threadIdx.x;
    if (idx < NS) {
      int node = snodes[idx];
      int s0 = row_ptr[node], e0 = row_ptr[node + 1];
      int pos = atomicAdd(n2cnt, e0 - s0 + 1);
      n2list[pos++] = node;
      for (int j = s0; j < e0; ++j) n2list[pos++] = pairs[j].x;
    }
  }
}

// ---------------- STAGE2: gather_h(H1->Es1) | prop2 (n2list, dupes benign) ----------------
__global__ void k_stage2(const uint2* __restrict__ H1, uint2* __restrict__ H2,
                         float4* __restrict__ Es1, const int* __restrict__ snodes,
                         const int* __restrict__ row_ptr, const int2* __restrict__ pairs,
                         const int* __restrict__ n2list, const int* __restrict__ n2cnt) {
  int b = blockIdx.x;
  if (b < 512) {
    d_gather_h(b, H1, Es1, snodes);
  } else {
    d_prop<1, 0, 0>(H1, H2, nullptr, row_ptr, pairs, n2list, n2cnt, 0, b - 512, 1024);
  }
}

// ---------------- STAGE3: gather_h(H2->Es2) | prop3 (samples -> Es3 fp32) ----------------
__global__ void k_stage3(const uint2* __restrict__ H2, float4* __restrict__ Es2,
                         float4* __restrict__ Es3, const int* __restrict__ snodes,
                         const int* __restrict__ row_ptr, const int2* __restrict__ pairs) {
  int b = blockIdx.x;
  if (b < 512) {
    d_gather_h(b, H2, Es2, snodes);
  } else {
    d_prop<1, 1, 1>(H2, nullptr, Es3, row_ptr, pairs, snodes, nullptr, NS, b - 512, 512);
  }
}

// ---------------- fused attention + pair scoring: one wave per pair ----------------
__global__ void k_attn3(const float* __restrict__ Es, const float* __restrict__ Mt,
                        const float* __restrict__ P, float* __restrict__ out) {
  __shared__ float sb[4][3 * 64];
  int wv = threadIdx.x >> 6, lane = threadIdx.x & 63;
  int w = blockIdx.x * 4 + wv;
  if (w >= BB) return;
  const float inv_scale = 0.17677669529663687f;  // 1/sqrt(32)
  const float* M0 = Mt;
  const float* M1 = Mt + 4096;
  const float* P0 = P;
  const float* P1 = P + 4096;
  float eo[2];
#pragma unroll
  for (int side = 0; side < 2; ++side) {
    int p = side ? (BB + w) : w;
    float e0 = Es[(size_t)0 * NS * DD + p * DD + lane];
    float e1 = Es[(size_t)1 * NS * DD + p * DD + lane];
    float e2 = Es[(size_t)2 * NS * DD + p * DD + lane];
    float e3 = Es[(size_t)3 * NS * DD + p * DD + lane];
    sb[wv][lane] = e0;

    float g0 = 0.f, g1 = 0.f;
#pragma unroll 8
    for (int b = 0; b < 64; ++b) {
      float eb = sb[wv][b];  // LDS same-address broadcast (wave-synchronous)
      g0 = fmaf(M0[b * 64 + lane], eb, g0);
      g1 = fmaf(M1[b * 64 + lane], eb, g1);
    }

    float el[4] = {e0, e1, e2, e3};
    float sc[4][2];
#pragma unroll
    for (int l = 0; l < 4; ++l) {
      float p0 = el[l] * g0, p1 = el[l] * g1;
#pragma unroll
      for (int o = 32; o; o >>= 1) {
        p0 += __shfl_xor(p0, o);
        p1 += __shfl_xor(p1, o);
      }
      sc[l][0] = p0 * inv_scale;
      sc[l][1] = p1 * inv_scale;
    }

    float ebar[2];
#pragma unroll
    for (int h = 0; h < 2; ++h) {
      float m = fmaxf(fmaxf(sc[0][h], sc[1][h]), fmaxf(sc[2][h], sc[3][h]));
      float x0 = expf(sc[0][h] - m), x1 = expf(sc[1][h] - m);
      float x2 = expf(sc[2][h] - m), x3 = expf(sc[3][h] - m);
      float inv = 1.f / (x0 + x1 + x2 + x3);
      ebar[h] = (x0 * e0 + x1 * e1 + x2 * e2 + x3 * e3) * inv;
    }
    sb[wv][64 + lane] = ebar[0];
    sb[wv][128 + lane] = ebar[1];

    float o = 0.f;
#pragma unroll 8
    for (int d = 0; d < 64; ++d) {
      float b0 = sb[wv][64 + d];
      float b1 = sb[wv][128 + d];
      o = fmaf(P0[d * 64 + lane], b0, o);
      o = fmaf(P1[d * 64 + lane], b1, o);
    }
    eo[side] = o;
  }
  float pd = eo[0] * eo[1];
#pragma unroll
  for (int o = 32; o; o >>= 1) pd += __shfl_xor(pd, o);
  if (lane == 0) out[w] = pd;
}

extern "C" void kernel_launch(void* const* d_in, const int* in_sizes, int n_in,
                              void* d_out, int out_size, void* d_ws, size_t ws_size,
                              hipStream_t stream) {
  const int* edge_src = (const int*)d_in[0];
  const int* edge_dst = (const int*)d_in[1];
  const float* edge_val = (const float*)d_in[2];
  const float* U_emb = (const float*)d_in[3];
  const float* V_emb = (const float*)d_in[4];
  const float* Wq = (const float*)d_in[5];
  const float* Wk = (const float*)d_in[6];
  const float* Wv = (const float*)d_in[7];
  const float* Wo = (const float*)d_in[8];
  const int* u = (const int*)d_in[9];
  const int* ii = (const int*)d_in[10];
  float* out = (float*)d_out;

  const float4* U4 = (const float4*)U_emb;
  const float4* V4 = (const float4*)V_emb;

  // workspace layout (16B-aligned base)
  float* Ea = (float*)d_ws;                          // H0 | H1 (fp16 tables, 25.6MB each)
  float* Eb = Ea + (size_t)NN * DD;                  // H2 (aliases c_sv scratch before)
  float* Es = Eb + (size_t)NN * DD;                  // 4*NS*64 fp32
  float* Mt = Es + (size_t)4 * NS * DD;              // 2*4096
  float* Pm = Mt + 8192;                             // 2*4096
  int* row_ptr = (int*)(Pm + 8192);                  // NN+1 (+pad)
  int* bcur = row_ptr + NN + 4;                      // NB2
  int* snodes = bcur + NB2;                          // NS
  int* n2cnt = snodes + NS;                          // 1
  uintptr_t pa = (uintptr_t)(n2cnt + 1);
  pa = (pa + 15) & ~(uintptr_t)15;
  int2* pairs = (int2*)pa;                           // NE int2

  uint2* H0 = (uint2*)Ea;                 // NN*16 uint2
  uint2* H1 = H0 + (size_t)NN * 16;
  uint2* H2 = (uint2*)Eb;                 // written after c_sv dead
  int2* c_sv = (int2*)Eb;                 // NB2*BCAP int2 = 12.8MB — dead after k_fine4m
  int* n2list = (int*)(Es + (size_t)3 * NS * DD);  // in Es[3] quarter; dead before stage3 writes

  float4* Es4 = (float4*)Es;

  k_pre<<<1, 256, 0, stream>>>(bcur, n2cnt);
  k_coarse2<<<(NE + CH2 - 1) / CH2, 256, 0, stream>>>(edge_src, edge_dst, edge_val, bcur, c_sv);
  k_fine4m<<<FB + CONVB + PREPB + BSB, 256, 0, stream>>>(bcur, c_sv, pairs, row_ptr, U4, V4, H0,
                                                         Wq, Wk, Wv, Wo, Mt, Pm, u, ii, snodes);
  k_prop1m<<<P1B + G0B + NLB, 256, 0, stream>>>(H0, H1, U4, V4, Es4 + (size_t)0 * NS * 16, snodes,
                                                row_ptr, pairs, n2list, n2cnt);
  k_stage2<<<512 + 1024, 256, 0, stream>>>(H1, H2, Es4 + (size_t)1 * NS * 16, snodes, row_ptr,
                                           pairs, n2list, n2cnt);
  k_stage3<<<512 + 512, 256, 0, stream>>>(H2, Es4 + (size_t)2 * NS * 16,
                                          Es4 + (size_t)3 * NS * 16, snodes, row_ptr, pairs);
  k_attn3<<<(BB + 3) / 4, 256, 0, stream>>>(Es, Mt, Pm, out);
}